// Round 12
// baseline (377.635 us; speedup 1.0000x reference)
//
#include <hip/hip_runtime.h>

#define N_NODES 20000
#define N_EDGES 320000
#define E_TOT   340000   // edges + self loops
#define N_GRAPHS 64
#define N_CLASSES 5
#define SLOPE 0.2f
#define EPS_BN 1e-5f

typedef short v8s __attribute__((ext_vector_type(8)));    // 8 bf16 (4 VGPRs)
typedef float v4f __attribute__((ext_vector_type(4)));    // 4 f32 acc
typedef _Float16 v4h __attribute__((ext_vector_type(4))); // 4 fp16 (8 B)

__device__ __forceinline__ float bfu2f(unsigned short u) {
    return __uint_as_float(((unsigned int)u) << 16);
}
__device__ __forceinline__ unsigned short f2bf(float f) {  // round-to-nearest-even
    unsigned int u = __float_as_uint(f);
    return (unsigned short)((u + 0x7FFF + ((u >> 16) & 1)) >> 16);
}

// ---------------- fused prep: weight splits + x->bf16 + zeros + gstart ----------------
#define SPQ (N_NODES * 512 / 4)
#define W1E (512 * 256)
#define W2E (256 * 256)
#define W3E (256 * 64)
#define ALZ (80000 * 4 + 20000 * 2)   // als1,ald1,als2,ald2 (4x80000) + als3,ald3 (2x20000)

__global__ __launch_bounds__(256) void k_prep(const float* __restrict__ x,
                                              unsigned short* __restrict__ xhi,
                                              const float* __restrict__ W1,
                                              unsigned short* __restrict__ bt1h, unsigned short* __restrict__ bt1l,
                                              const float* __restrict__ W2,
                                              unsigned short* __restrict__ bt2h, unsigned short* __restrict__ bt2l,
                                              const float* __restrict__ W3,
                                              unsigned short* __restrict__ bt3h, unsigned short* __restrict__ bt3l,
                                              const int* __restrict__ batch, int* __restrict__ gstart,
                                              int* __restrict__ cnt, float* __restrict__ sums,
                                              float* __restrict__ albase) {
    int id = blockIdx.x * 256 + threadIdx.x;
    if (id < SPQ) {
        const float4 v = *(const float4*)(x + (size_t)id * 4);
        ushort4 h;
        h.x = f2bf(v.x); h.y = f2bf(v.y); h.z = f2bf(v.z); h.w = f2bf(v.w);
        *(ushort4*)(xhi + (size_t)id * 4) = h;
        return;
    }
    id -= SPQ;
    if (id < W1E) {
        const int K = 512, N = 256;
        int n = id / K, k = id - n * K;
        float f = W1[(size_t)k * N + n];
        unsigned short h = f2bf(f);
        bt1h[id] = h;
        bt1l[id] = f2bf(f - bfu2f(h));
        return;
    }
    id -= W1E;
    if (id < W2E) {
        const int K = 256, N = 256;
        int n = id / K, k = id - n * K;
        float f = W2[(size_t)k * N + n];
        unsigned short h = f2bf(f);
        bt2h[id] = h;
        bt2l[id] = f2bf(f - bfu2f(h));
        return;
    }
    id -= W2E;
    if (id < W3E) {
        const int K = 256, N = 64;
        int n = id / K, k = id - n * K;
        float f = W3[(size_t)k * N + n];
        unsigned short h = f2bf(f);
        bt3h[id] = h;
        bt3l[id] = f2bf(f - bfu2f(h));
        return;
    }
    id -= W3E;
    if (id < N_NODES) {
        int i = id;
        int b = batch[i];
        if (i == 0) {
            for (int g = 0; g <= b; ++g) gstart[g] = 0;
        } else {
            int p = batch[i - 1];
            for (int g = p + 1; g <= b; ++g) gstart[g] = i;
        }
        if (i == N_NODES - 1) {
            for (int g = b + 1; g <= N_GRAPHS; ++g) gstart[g] = N_NODES;
        }
        return;
    }
    id -= N_NODES;
    if (id < N_NODES) { cnt[id] = 0; return; }
    id -= N_NODES;
    if (id < N_GRAPHS * 64) { sums[id] = 0.f; return; }
    id -= N_GRAPHS * 64;
    if (id < ALZ) albase[id] = 0.f;
}

// ---------------- CSR build ----------------
__global__ void k_count(const int* __restrict__ ei, int* __restrict__ cnt) {
    int e = blockIdx.x * 256 + threadIdx.x;
    if (e >= E_TOT) return;
    int d = (e < N_EDGES) ? ei[N_EDGES + e] : (e - N_EDGES);
    atomicAdd(&cnt[d], 1);
}

__global__ __launch_bounds__(1024) void k_scan(const int* __restrict__ cnt,
                                               int* __restrict__ indptr,
                                               int* __restrict__ wptr) {
    __shared__ int smem[1024];
    const int t = threadIdx.x;
    const int per = (N_NODES + 1023) / 1024;  // 20
    const int i0 = t * per;
    int lsum = 0;
    for (int j = 0; j < per; ++j) {
        int i = i0 + j;
        if (i < N_NODES) lsum += cnt[i];
    }
    smem[t] = lsum;
    __syncthreads();
    for (int off = 1; off < 1024; off <<= 1) {
        int v = (t >= off) ? smem[t - off] : 0;
        __syncthreads();
        smem[t] += v;
        __syncthreads();
    }
    int run = smem[t] - lsum;  // exclusive prefix
    for (int j = 0; j < per; ++j) {
        int i = i0 + j;
        if (i < N_NODES) {
            indptr[i] = run;
            wptr[i] = run;
            run += cnt[i];
        }
    }
    if (t == 1023) indptr[N_NODES] = E_TOT;
}

__global__ void k_scatter(const int* __restrict__ ei, int* __restrict__ wptr,
                          int* __restrict__ esrc) {
    int e = blockIdx.x * 256 + threadIdx.x;
    if (e >= E_TOT) return;
    int s, d;
    if (e < N_EDGES) { s = ei[e]; d = ei[N_EDGES + e]; }
    else             { s = d = e - N_EDGES; }
    int pos = atomicAdd(&wptr[d], 1);
    esrc[pos] = s;
}

// ---------------- MFMA GEMM, 64-row blocks, coalesced LDS-staged B, fp16 C, fused logits ----------------
template <int TN, bool SPLITA>
__global__ __launch_bounds__(256) void k_gemm_mfma(const unsigned short* __restrict__ Ahi,
                                                   const unsigned short* __restrict__ Alo,
                                                   const unsigned short* __restrict__ Bth,
                                                   const unsigned short* __restrict__ Btl,
                                                   _Float16* __restrict__ H,
                                                   const float* __restrict__ aw_s,
                                                   const float* __restrict__ aw_d,
                                                   float* __restrict__ als,
                                                   float* __restrict__ ald,
                                                   int HS,          // head stride of als/ald (4 or 1)
                                                   int M, int K, int N) {
    constexpr int NTB = 2 * TN;             // n-tiles per block
    constexpr int NFRAG = 2 * NTB * 64;     // fragments per plane per K-chunk (2 ksteps)
    constexpr int LDSW = NFRAG * 8 + (NFRAG >> 4) * 8;  // shorts, with skew padding
    __shared__ short lbh[LDSW];
    __shared__ short lbl[LDSW];
    const int tid = threadIdx.x;
    const int wave = tid >> 6, lane = tid & 63;
    const int wr = wave >> 1, wc = wave & 1;   // 2x2 wave grid
    const int q = lane >> 4, r = lane & 15;
    const int m0 = blockIdx.x * 64 + wr * 32;
    const int n0 = blockIdx.y * (NTB * 16);
    size_t abase[2];
#pragma unroll
    for (int mi = 0; mi < 2; ++mi) {
        int ar = m0 + mi * 16 + r;
        if (ar >= M) ar = M - 1;               // clamp; stores guarded
        abase[mi] = (size_t)ar * K + q * 8;
    }
    v4f acc[2][TN];
#pragma unroll
    for (int mi = 0; mi < 2; ++mi)
#pragma unroll
        for (int t = 0; t < TN; ++t) acc[mi][t] = (v4f){0.f, 0.f, 0.f, 0.f};

    for (int kc = 0; kc < K; kc += 64) {
        __syncthreads();
        // coalesced staging: f -> qq(f&3), ss(bit2), rr(bits3-6), tt(bits7+)
        for (int f = tid; f < NFRAG; f += 256) {
            const int qq = f & 3;
            const int ss = (f >> 2) & 1;
            const int rr = (f >> 3) & 15;
            const int tt = f >> 7;
            const size_t g = (size_t)(n0 + tt * 16 + rr) * K + kc + ss * 32 + qq * 8;
            const int fi = (ss * NTB + tt) * 64 + qq * 16 + rr;
            const int off = fi * 8 + (fi >> 4) * 8;   // 16B skew per 16 frags
            *(v8s*)&lbh[off] = *(const v8s*)(Bth + g);
            *(v8s*)&lbl[off] = *(const v8s*)(Btl + g);
        }
        __syncthreads();
#pragma unroll
        for (int ss = 0; ss < 2; ++ss) {
            v8s ah[2], al[2];
#pragma unroll
            for (int mi = 0; mi < 2; ++mi) {
                ah[mi] = *(const v8s*)(Ahi + abase[mi] + kc + ss * 32);
                if constexpr (SPLITA) al[mi] = *(const v8s*)(Alo + abase[mi] + kc + ss * 32);
            }
#pragma unroll
            for (int t = 0; t < TN; ++t) {
                const int fib = (ss * NTB + wc * TN + t) * 4 + q;
                const int off = (fib * 16 + r) * 8 + fib * 8;   // matches staging skew
                const v8s bh = *(const v8s*)&lbh[off];
                const v8s bl = *(const v8s*)&lbl[off];
#pragma unroll
                for (int mi = 0; mi < 2; ++mi) {
                    acc[mi][t] = __builtin_amdgcn_mfma_f32_16x16x32_bf16(ah[mi], bh, acc[mi][t], 0, 0, 0);
                    acc[mi][t] = __builtin_amdgcn_mfma_f32_16x16x32_bf16(ah[mi], bl, acc[mi][t], 0, 0, 0);
                    if constexpr (SPLITA)
                        acc[mi][t] = __builtin_amdgcn_mfma_f32_16x16x32_bf16(al[mi], bh, acc[mi][t], 0, 0, 0);
                }
            }
        }
    }
    // C/D layout: col = lane&15, row = quad*4 + reg; store fp16
#pragma unroll
    for (int mi = 0; mi < 2; ++mi)
#pragma unroll
        for (int t = 0; t < TN; ++t)
#pragma unroll
            for (int i = 0; i < 4; ++i) {
                const int row = m0 + mi * 16 + q * 4 + i;
                if (row < M) H[(size_t)row * N + n0 + (wc * TN + t) * 16 + r] = (_Float16)acc[mi][t][i];
            }
    // fused attention-logit partials: each wave's columns lie in one head
    const int colbase = n0 + wc * TN * 16;
    const int hd = colbase >> 6;
#pragma unroll
    for (int mi = 0; mi < 2; ++mi)
#pragma unroll
        for (int i = 0; i < 4; ++i) {
            float sp = 0.f, dp = 0.f;
#pragma unroll
            for (int t = 0; t < TN; ++t) {
                const int col = colbase + t * 16 + r;
                sp += acc[mi][t][i] * aw_s[col];
                dp += acc[mi][t][i] * aw_d[col];
            }
#pragma unroll
            for (int m = 1; m < 16; m <<= 1) {
                sp += __shfl_xor(sp, m, 64);
                dp += __shfl_xor(dp, m, 64);
            }
            const int row = m0 + mi * 16 + q * 4 + i;
            if (r == 0 && row < M) {
                atomicAdd(&als[row * HS + hd], sp);
                atomicAdd(&ald[row * HS + hd], dp);
            }
        }
}

// ---------------- GAT aggregate, 2 waves per node (halved gather chain), fp16, 4-wide ----------------
// Block = 256 thr = 2 nodes x 2 waves. Each wave aggregates half the edge list
// (online-softmax partials are additive); wave 1 deposits partials in LDS,
// wave 0 combines and runs the bias+BN+ReLU+split epilogue.
__global__ __launch_bounds__(256) void k_agg4(const _Float16* __restrict__ hin,
                                              const float* __restrict__ als,
                                              const float* __restrict__ ald,
                                              const int* __restrict__ indptr,
                                              const int* __restrict__ esrc,
                                              const float* __restrict__ bias,
                                              const float* __restrict__ gamma,
                                              const float* __restrict__ beta,
                                              const float* __restrict__ mean,
                                              const float* __restrict__ var,
                                              unsigned short* __restrict__ phi,
                                              unsigned short* __restrict__ plo) {
    __shared__ float lacc[2][64][4];
    __shared__ float lsm[2][64];
    const int pair = threadIdx.x >> 7;          // node within block (0..1)
    const int wv   = (threadIdx.x >> 6) & 1;    // wave within pair
    const int lane = threadIdx.x & 63;
    const int n = blockIdx.x * 2 + pair;
    const int beg = indptr[n], end = indptr[n + 1];
    const int mid = beg + ((end - beg + 1) >> 1);
    const int e0 = wv ? mid : beg;
    const int e1 = wv ? end : mid;
    const int head = lane >> 4;
    const float aldn = ald[n * 4 + head];
    float4 acc = {0.f, 0.f, 0.f, 0.f};
    float sm = 0.f;
    const int c = lane * 4;
    int e = e0;
    for (; e + 3 < e1; e += 4) {       // 4 independent gather chains in flight
        const int s0 = esrc[e], s1 = esrc[e + 1], s2 = esrc[e + 2], s3 = esrc[e + 3];
        float v0 = als[s0 * 4 + head] + aldn;
        float v1 = als[s1 * 4 + head] + aldn;
        float v2 = als[s2 * 4 + head] + aldn;
        float v3 = als[s3 * 4 + head] + aldn;
        const v4h h0 = *(const v4h*)(hin + (size_t)s0 * 256 + c);
        const v4h h1 = *(const v4h*)(hin + (size_t)s1 * 256 + c);
        const v4h h2 = *(const v4h*)(hin + (size_t)s2 * 256 + c);
        const v4h h3 = *(const v4h*)(hin + (size_t)s3 * 256 + c);
        v0 = (v0 > 0.f) ? v0 : SLOPE * v0;
        v1 = (v1 > 0.f) ? v1 : SLOPE * v1;
        v2 = (v2 > 0.f) ? v2 : SLOPE * v2;
        v3 = (v3 > 0.f) ? v3 : SLOPE * v3;
        const float a0 = __expf(v0), a1 = __expf(v1), a2 = __expf(v2), a3 = __expf(v3);
        sm += (a0 + a1) + (a2 + a3);
        acc.x += a0 * (float)h0.x + a1 * (float)h1.x + a2 * (float)h2.x + a3 * (float)h3.x;
        acc.y += a0 * (float)h0.y + a1 * (float)h1.y + a2 * (float)h2.y + a3 * (float)h3.y;
        acc.z += a0 * (float)h0.z + a1 * (float)h1.z + a2 * (float)h2.z + a3 * (float)h3.z;
        acc.w += a0 * (float)h0.w + a1 * (float)h1.w + a2 * (float)h2.w + a3 * (float)h3.w;
    }
    for (; e < e1; ++e) {
        const int s0 = esrc[e];
        float v0 = als[s0 * 4 + head] + aldn;
        const v4h h0 = *(const v4h*)(hin + (size_t)s0 * 256 + c);
        v0 = (v0 > 0.f) ? v0 : SLOPE * v0;
        const float a0 = __expf(v0);
        sm += a0;
        acc.x += a0 * (float)h0.x; acc.y += a0 * (float)h0.y;
        acc.z += a0 * (float)h0.z; acc.w += a0 * (float)h0.w;
    }
    if (wv == 1) {
        lacc[pair][lane][0] = acc.x; lacc[pair][lane][1] = acc.y;
        lacc[pair][lane][2] = acc.z; lacc[pair][lane][3] = acc.w;
        lsm[pair][lane] = sm;
    }
    __syncthreads();
    if (wv == 0) {
        acc.x += lacc[pair][lane][0]; acc.y += lacc[pair][lane][1];
        acc.z += lacc[pair][lane][2]; acc.w += lacc[pair][lane][3];
        sm += lsm[pair][lane];
        const float invd = 1.f / (sm + 1e-16f);
        float y[4] = {acc.x * invd, acc.y * invd, acc.z * invd, acc.w * invd};
        ushort4 oh, ol;
        unsigned short* ph = &oh.x;
        unsigned short* pl = &ol.x;
#pragma unroll
        for (int i = 0; i < 4; ++i) {
            float t = y[i] + bias[c + i];
            t = (t - mean[c + i]) * rsqrtf(var[c + i] + EPS_BN) * gamma[c + i] + beta[c + i];
            t = fmaxf(t, 0.f);
            unsigned short h = f2bf(t);
            ph[i] = h;
            pl[i] = f2bf(t - bfu2f(h));
        }
        *(ushort4*)(phi + (size_t)n * 256 + c) = oh;
        *(ushort4*)(plo + (size_t)n * 256 + c) = ol;
    }
}

// ---------------- fused GAT aggregate (1 head) + bias + ReLU + pool-scatter ----------------
__global__ __launch_bounds__(256) void k_agg1(const _Float16* __restrict__ hin,
                                              const float* __restrict__ als,
                                              const float* __restrict__ ald,
                                              const int* __restrict__ indptr,
                                              const int* __restrict__ esrc,
                                              const float* __restrict__ bias,
                                              const int* __restrict__ batch,
                                              float* __restrict__ sums) {
    const int n = blockIdx.x * 4 + (threadIdx.x >> 6);
    const int lane = threadIdx.x & 63;
    const int beg = indptr[n], end = indptr[n + 1];
    const float aldn = ald[n];
    float acc = 0.f, sm = 0.f;
    int e = beg;
    for (; e + 3 < end; e += 4) {
        const int s0 = esrc[e], s1 = esrc[e + 1], s2 = esrc[e + 2], s3 = esrc[e + 3];
        float v0 = als[s0] + aldn;
        float v1 = als[s1] + aldn;
        float v2 = als[s2] + aldn;
        float v3 = als[s3] + aldn;
        const float h0 = (float)hin[(size_t)s0 * 64 + lane];
        const float h1 = (float)hin[(size_t)s1 * 64 + lane];
        const float h2 = (float)hin[(size_t)s2 * 64 + lane];
        const float h3 = (float)hin[(size_t)s3 * 64 + lane];
        v0 = (v0 > 0.f) ? v0 : SLOPE * v0;
        v1 = (v1 > 0.f) ? v1 : SLOPE * v1;
        v2 = (v2 > 0.f) ? v2 : SLOPE * v2;
        v3 = (v3 > 0.f) ? v3 : SLOPE * v3;
        const float a0 = __expf(v0), a1 = __expf(v1), a2 = __expf(v2), a3 = __expf(v3);
        sm += (a0 + a1) + (a2 + a3);
        acc += a0 * h0 + a1 * h1 + a2 * h2 + a3 * h3;
    }
    for (; e < end; ++e) {
        const int s0 = esrc[e];
        float v0 = als[s0] + aldn;
        const float h0 = (float)hin[(size_t)s0 * 64 + lane];
        v0 = (v0 > 0.f) ? v0 : SLOPE * v0;
        const float a0 = __expf(v0);
        sm += a0;
        acc += a0 * h0;
    }
    const float invd = 1.f / (sm + 1e-16f);
    const float val = fmaxf(acc * invd + bias[lane], 0.f);
    atomicAdd(&sums[batch[n] * 64 + lane], val);
}

__global__ void k_mlp(const float* __restrict__ sums, const int* __restrict__ gstart,
                      const float* __restrict__ w1, const float* __restrict__ b1,
                      const float* __restrict__ w2, const float* __restrict__ b2,
                      float* __restrict__ outp) {
    const int g = blockIdx.x;
    const int t = threadIdx.x;  // 32
    __shared__ float hid[32];
    const int cntn = gstart[g + 1] - gstart[g];
    const float inv = 1.f / (float)max(cntn, 1);
    float acc = b1[t];
    for (int c = 0; c < 64; ++c) acc += (sums[g * 64 + c] * inv) * w1[c * 32 + t];
    hid[t] = fmaxf(acc, 0.f);
    __syncthreads();
    if (t < N_CLASSES) {
        float o = b2[t];
        for (int k = 0; k < 32; ++k) o += hid[k] * w2[k * 5 + t];
        outp[g * 5 + t] = o;
    }
}

extern "C" void kernel_launch(void* const* d_in, const int* in_sizes, int n_in,
                              void* d_out, int out_size, void* d_ws, size_t ws_size,
                              hipStream_t stream) {
    const float* x        = (const float*)d_in[0];
    const int* edge_index = (const int*)d_in[1];
    const int* batch      = (const int*)d_in[2];
    const float* W1  = (const float*)d_in[3];
    const float* a1s = (const float*)d_in[4];
    const float* a1d = (const float*)d_in[5];
    const float* b1  = (const float*)d_in[6];
    const float* g1  = (const float*)d_in[7];
    const float* be1 = (const float*)d_in[8];
    const float* mu1 = (const float*)d_in[9];
    const float* va1 = (const float*)d_in[10];
    const float* W2  = (const float*)d_in[11];
    const float* a2s = (const float*)d_in[12];
    const float* a2d = (const float*)d_in[13];
    const float* b2  = (const float*)d_in[14];
    const float* g2  = (const float*)d_in[15];
    const float* be2 = (const float*)d_in[16];
    const float* mu2 = (const float*)d_in[17];
    const float* va2 = (const float*)d_in[18];
    const float* W3  = (const float*)d_in[19];
    const float* a3s = (const float*)d_in[20];
    const float* a3d = (const float*)d_in[21];
    const float* b3  = (const float*)d_in[22];
    const float* l1w = (const float*)d_in[23];
    const float* l1b = (const float*)d_in[24];
    const float* l2w = (const float*)d_in[25];
    const float* l2b = (const float*)d_in[26];
    float* out = (float*)d_out;

    char* w = (char*)d_ws;
    size_t off = 0;
    auto alloc = [&](size_t bytes) -> void* {
        void* p = w + off;
        off += (bytes + 255) & ~(size_t)255;
        return p;
    };
    unsigned short* xhi = (unsigned short*)alloc((size_t)N_NODES * 512 * 2);
    unsigned short* phi = xhi;                              // 20000*256 shorts
    unsigned short* plo = xhi + (size_t)N_NODES * 256;      // 20000*256 shorts
    _Float16* bufH  = (_Float16*)alloc((size_t)N_NODES * 256 * 2);  // GEMM1/2 out (fp16)
    _Float16* bufH3 = (_Float16*)alloc((size_t)N_NODES * 64 * 2);   // GEMM3 out (fp16)
    unsigned short* bt1h = (unsigned short*)alloc((size_t)512 * 256 * 2);
    unsigned short* bt1l = (unsigned short*)alloc((size_t)512 * 256 * 2);
    unsigned short* bt2h = (unsigned short*)alloc((size_t)256 * 256 * 2);
    unsigned short* bt2l = (unsigned short*)alloc((size_t)256 * 256 * 2);
    unsigned short* bt3h = (unsigned short*)alloc((size_t)256 * 64 * 2);
    unsigned short* bt3l = (unsigned short*)alloc((size_t)256 * 64 * 2);
    float* albase = (float*)alloc((size_t)ALZ * 4);  // als1,ald1,als2,ald2,als3,ald3
    float* als1 = albase;
    float* ald1 = albase + 80000;
    float* als2 = albase + 160000;
    float* ald2 = albase + 240000;
    float* als3 = albase + 320000;
    float* ald3 = albase + 340000;
    int* cnt      = (int*)alloc((size_t)N_NODES * 4);
    int* wptr     = (int*)alloc((size_t)N_NODES * 4);
    int* indptr   = (int*)alloc((size_t)(N_NODES + 1) * 4);
    int* esrc     = (int*)alloc((size_t)E_TOT * 4);
    int* gstart   = (int*)alloc((size_t)(N_GRAPHS + 1) * 4);
    float* sums   = (float*)alloc((size_t)N_GRAPHS * 64 * 4);

    // fused prep (weight splits, x->bf16, gstart, all zero-inits)
    const int PREP_IDS = SPQ + W1E + W2E + W3E + N_NODES + N_NODES + N_GRAPHS * 64 + ALZ;
    k_prep<<<(PREP_IDS + 255) / 256, 256, 0, stream>>>(x, xhi, W1, bt1h, bt1l, W2, bt2h, bt2l,
                                                       W3, bt3h, bt3l, batch, gstart, cnt, sums, albase);
    // CSR by dst (graph identical for all 3 layers)
    k_count<<<(E_TOT + 255) / 256, 256, 0, stream>>>(edge_index, cnt);
    k_scan<<<1, 1024, 0, stream>>>(cnt, indptr, wptr);
    k_scatter<<<(E_TOT + 255) / 256, 256, 0, stream>>>(edge_index, wptr, esrc);

    const int MB = (N_NODES + 63) / 64;  // 313 blocks of 64 rows

    // layer 1 (A = rne(x), 2 MFMA passes); logits fused into epilogue
    k_gemm_mfma<4, false><<<dim3(MB, 2), 256, 0, stream>>>(xhi, (const unsigned short*)nullptr,
                                                           bt1h, bt1l, bufH, a1s, a1d, als1, ald1, 4,
                                                           N_NODES, 512, 256);
    k_agg4<<<N_NODES / 2, 256, 0, stream>>>(bufH, als1, ald1, indptr, esrc, b1, g1, be1, mu1, va1, phi, plo);
    // layer 2 (A = hi/lo planes, 3 passes)
    k_gemm_mfma<4, true><<<dim3(MB, 2), 256, 0, stream>>>(phi, plo, bt2h, bt2l, bufH, a2s, a2d, als2, ald2, 4,
                                                          N_NODES, 256, 256);
    k_agg4<<<N_NODES / 2, 256, 0, stream>>>(bufH, als2, ald2, indptr, esrc, b2, g2, be2, mu2, va2, phi, plo);
    // layer 3
    k_gemm_mfma<2, true><<<dim3(MB, 1), 256, 0, stream>>>(phi, plo, bt3h, bt3l, bufH3, a3s, a3d, als3, ald3, 1,
                                                          N_NODES, 256, 64);
    k_agg1<<<N_NODES / 4, 256, 0, stream>>>(bufH3, als3, ald3, indptr, esrc, b3, batch, sums);
    // readout
    k_mlp<<<N_GRAPHS, 32, 0, stream>>>(sums, gstart, l1w, l1b, l2w, l2b, out);
}

// Round 13
// 366.658 us; speedup vs baseline: 1.0299x; 1.0299x over previous
//
#include <hip/hip_runtime.h>

#define N_NODES 20000
#define N_EDGES 320000
#define E_TOT   340000   // edges + self loops
#define N_GRAPHS 64
#define N_CLASSES 5
#define SLOPE 0.2f
#define EPS_BN 1e-5f

typedef short v8s __attribute__((ext_vector_type(8)));    // 8 bf16 (4 VGPRs)
typedef float v4f __attribute__((ext_vector_type(4)));    // 4 f32 acc
typedef _Float16 v4h __attribute__((ext_vector_type(4))); // 4 fp16 (8 B)

__device__ __forceinline__ float bfu2f(unsigned short u) {
    return __uint_as_float(((unsigned int)u) << 16);
}
__device__ __forceinline__ unsigned short f2bf(float f) {  // round-to-nearest-even
    unsigned int u = __float_as_uint(f);
    return (unsigned short)((u + 0x7FFF + ((u >> 16) & 1)) >> 16);
}

// ---------------- fused prep: weight splits + x->bf16 + zeros + gstart ----------------
#define SPQ (N_NODES * 512 / 4)
#define W1E (512 * 256)
#define W2E (256 * 256)
#define W3E (256 * 64)
#define ALZ (80000 * 4 + 20000 * 2)   // als1,ald1,als2,ald2 (4x80000) + als3,ald3 (2x20000)

__global__ __launch_bounds__(256) void k_prep(const float* __restrict__ x,
                                              unsigned short* __restrict__ xhi,
                                              const float* __restrict__ W1,
                                              unsigned short* __restrict__ bt1h, unsigned short* __restrict__ bt1l,
                                              const float* __restrict__ W2,
                                              unsigned short* __restrict__ bt2h, unsigned short* __restrict__ bt2l,
                                              const float* __restrict__ W3,
                                              unsigned short* __restrict__ bt3h, unsigned short* __restrict__ bt3l,
                                              const int* __restrict__ batch, int* __restrict__ gstart,
                                              int* __restrict__ cnt, float* __restrict__ sums,
                                              float* __restrict__ albase) {
    int id = blockIdx.x * 256 + threadIdx.x;
    if (id < SPQ) {
        const float4 v = *(const float4*)(x + (size_t)id * 4);
        ushort4 h;
        h.x = f2bf(v.x); h.y = f2bf(v.y); h.z = f2bf(v.z); h.w = f2bf(v.w);
        *(ushort4*)(xhi + (size_t)id * 4) = h;
        return;
    }
    id -= SPQ;
    if (id < W1E) {
        const int K = 512, N = 256;
        int n = id / K, k = id - n * K;
        float f = W1[(size_t)k * N + n];
        unsigned short h = f2bf(f);
        bt1h[id] = h;
        bt1l[id] = f2bf(f - bfu2f(h));
        return;
    }
    id -= W1E;
    if (id < W2E) {
        const int K = 256, N = 256;
        int n = id / K, k = id - n * K;
        float f = W2[(size_t)k * N + n];
        unsigned short h = f2bf(f);
        bt2h[id] = h;
        bt2l[id] = f2bf(f - bfu2f(h));
        return;
    }
    id -= W2E;
    if (id < W3E) {
        const int K = 256, N = 64;
        int n = id / K, k = id - n * K;
        float f = W3[(size_t)k * N + n];
        unsigned short h = f2bf(f);
        bt3h[id] = h;
        bt3l[id] = f2bf(f - bfu2f(h));
        return;
    }
    id -= W3E;
    if (id < N_NODES) {
        int i = id;
        int b = batch[i];
        if (i == 0) {
            for (int g = 0; g <= b; ++g) gstart[g] = 0;
        } else {
            int p = batch[i - 1];
            for (int g = p + 1; g <= b; ++g) gstart[g] = i;
        }
        if (i == N_NODES - 1) {
            for (int g = b + 1; g <= N_GRAPHS; ++g) gstart[g] = N_NODES;
        }
        return;
    }
    id -= N_NODES;
    if (id < N_NODES) { cnt[id] = 0; return; }
    id -= N_NODES;
    if (id < N_GRAPHS * 64) { sums[id] = 0.f; return; }
    id -= N_GRAPHS * 64;
    if (id < ALZ) albase[id] = 0.f;
}

// ---------------- CSR build ----------------
__global__ void k_count(const int* __restrict__ ei, int* __restrict__ cnt) {
    int e = blockIdx.x * 256 + threadIdx.x;
    if (e >= E_TOT) return;
    int d = (e < N_EDGES) ? ei[N_EDGES + e] : (e - N_EDGES);
    atomicAdd(&cnt[d], 1);
}

__global__ __launch_bounds__(1024) void k_scan(const int* __restrict__ cnt,
                                               int* __restrict__ indptr,
                                               int* __restrict__ wptr) {
    __shared__ int smem[1024];
    const int t = threadIdx.x;
    const int per = (N_NODES + 1023) / 1024;  // 20
    const int i0 = t * per;
    int lsum = 0;
    for (int j = 0; j < per; ++j) {
        int i = i0 + j;
        if (i < N_NODES) lsum += cnt[i];
    }
    smem[t] = lsum;
    __syncthreads();
    for (int off = 1; off < 1024; off <<= 1) {
        int v = (t >= off) ? smem[t - off] : 0;
        __syncthreads();
        smem[t] += v;
        __syncthreads();
    }
    int run = smem[t] - lsum;  // exclusive prefix
    for (int j = 0; j < per; ++j) {
        int i = i0 + j;
        if (i < N_NODES) {
            indptr[i] = run;
            wptr[i] = run;
            run += cnt[i];
        }
    }
    if (t == 1023) indptr[N_NODES] = E_TOT;
}

__global__ void k_scatter(const int* __restrict__ ei, int* __restrict__ wptr,
                          int* __restrict__ esrc) {
    int e = blockIdx.x * 256 + threadIdx.x;
    if (e >= E_TOT) return;
    int s, d;
    if (e < N_EDGES) { s = ei[e]; d = ei[N_EDGES + e]; }
    else             { s = d = e - N_EDGES; }
    int pos = atomicAdd(&wptr[d], 1);
    esrc[pos] = s;
}

// ---------------- MFMA GEMM, 64-row blocks, coalesced LDS-staged B with REGISTER
// DOUBLE-BUFFER (next K-chunk's fragments prefetched into VGPRs during the MFMA
// phase, so the barrier-bracketed section is pure LDS writes), fp16 C, fused logits.
// KK is compile-time so the K-loop fully unrolls and ping-pong copies vanish.
template <int TN, bool SPLITA, int KK>
__global__ __launch_bounds__(256) void k_gemm_mfma(const unsigned short* __restrict__ Ahi,
                                                   const unsigned short* __restrict__ Alo,
                                                   const unsigned short* __restrict__ Bth,
                                                   const unsigned short* __restrict__ Btl,
                                                   _Float16* __restrict__ H,
                                                   const float* __restrict__ aw_s,
                                                   const float* __restrict__ aw_d,
                                                   float* __restrict__ als,
                                                   float* __restrict__ ald,
                                                   int HS,          // head stride of als/ald (4 or 1)
                                                   int M, int N) {
    constexpr int NTB = 2 * TN;             // n-tiles per block
    constexpr int NFRAG = 2 * NTB * 64;     // fragments per plane per K-chunk (2 ksteps)
    constexpr int NITER = NFRAG / 256;      // staging iterations per thread
    constexpr int LDSW = NFRAG * 8 + (NFRAG >> 4) * 8;  // shorts, with skew padding
    __shared__ short lbh[LDSW];
    __shared__ short lbl[LDSW];
    const int tid = threadIdx.x;
    const int wave = tid >> 6, lane = tid & 63;
    const int wr = wave >> 1, wc = wave & 1;   // 2x2 wave grid
    const int q = lane >> 4, r = lane & 15;
    const int m0 = blockIdx.x * 64 + wr * 32;
    const int n0 = blockIdx.y * (NTB * 16);
    size_t abase[2];
#pragma unroll
    for (int mi = 0; mi < 2; ++mi) {
        int ar = m0 + mi * 16 + r;
        if (ar >= M) ar = M - 1;               // clamp; stores guarded
        abase[mi] = (size_t)ar * KK + q * 8;
    }
    // per-thread staging addresses (coalesced: qq/ss in low tid bits) + LDS offsets
    size_t gaddr[NITER];
    int loff[NITER];
#pragma unroll
    for (int j = 0; j < NITER; ++j) {
        const int f = tid + j * 256;
        const int qq = f & 3;
        const int ss = (f >> 2) & 1;
        const int rr = (f >> 3) & 15;
        const int tt = f >> 7;
        gaddr[j] = (size_t)(n0 + tt * 16 + rr) * KK + ss * 32 + qq * 8;
        const int fi = (ss * NTB + tt) * 64 + qq * 16 + rr;
        loff[j] = fi * 8 + (fi >> 4) * 8;   // 16B skew per 16 frags
    }
    v4f acc[2][TN];
#pragma unroll
    for (int mi = 0; mi < 2; ++mi)
#pragma unroll
        for (int t = 0; t < TN; ++t) acc[mi][t] = (v4f){0.f, 0.f, 0.f, 0.f};

    // preload chunk 0 into registers
    v8s ch[NITER], cl[NITER];
#pragma unroll
    for (int j = 0; j < NITER; ++j) {
        ch[j] = *(const v8s*)(Bth + gaddr[j]);
        cl[j] = *(const v8s*)(Btl + gaddr[j]);
    }

#pragma unroll
    for (int kc = 0; kc < KK; kc += 64) {
        __syncthreads();
#pragma unroll
        for (int j = 0; j < NITER; ++j) {
            *(v8s*)&lbh[loff[j]] = ch[j];
            *(v8s*)&lbl[loff[j]] = cl[j];
        }
        __syncthreads();
        if (kc + 64 < KK) {     // prefetch next chunk; overlaps with MFMA below
#pragma unroll
            for (int j = 0; j < NITER; ++j) {
                ch[j] = *(const v8s*)(Bth + gaddr[j] + kc + 64);
                cl[j] = *(const v8s*)(Btl + gaddr[j] + kc + 64);
            }
        }
#pragma unroll
        for (int ss = 0; ss < 2; ++ss) {
            v8s ah[2], al[2];
#pragma unroll
            for (int mi = 0; mi < 2; ++mi) {
                ah[mi] = *(const v8s*)(Ahi + abase[mi] + kc + ss * 32);
                if constexpr (SPLITA) al[mi] = *(const v8s*)(Alo + abase[mi] + kc + ss * 32);
            }
#pragma unroll
            for (int t = 0; t < TN; ++t) {
                const int fib = (ss * NTB + wc * TN + t) * 4 + q;
                const int off = (fib * 16 + r) * 8 + fib * 8;   // matches staging skew
                const v8s bh = *(const v8s*)&lbh[off];
                const v8s bl = *(const v8s*)&lbl[off];
#pragma unroll
                for (int mi = 0; mi < 2; ++mi) {
                    acc[mi][t] = __builtin_amdgcn_mfma_f32_16x16x32_bf16(ah[mi], bh, acc[mi][t], 0, 0, 0);
                    acc[mi][t] = __builtin_amdgcn_mfma_f32_16x16x32_bf16(ah[mi], bl, acc[mi][t], 0, 0, 0);
                    if constexpr (SPLITA)
                        acc[mi][t] = __builtin_amdgcn_mfma_f32_16x16x32_bf16(al[mi], bh, acc[mi][t], 0, 0, 0);
                }
            }
        }
    }
    // C/D layout: col = lane&15, row = quad*4 + reg; store fp16
#pragma unroll
    for (int mi = 0; mi < 2; ++mi)
#pragma unroll
        for (int t = 0; t < TN; ++t)
#pragma unroll
            for (int i = 0; i < 4; ++i) {
                const int row = m0 + mi * 16 + q * 4 + i;
                if (row < M) H[(size_t)row * N + n0 + (wc * TN + t) * 16 + r] = (_Float16)acc[mi][t][i];
            }
    // fused attention-logit partials: each wave's columns lie in one head
    const int colbase = n0 + wc * TN * 16;
    const int hd = colbase >> 6;
#pragma unroll
    for (int mi = 0; mi < 2; ++mi)
#pragma unroll
        for (int i = 0; i < 4; ++i) {
            float sp = 0.f, dp = 0.f;
#pragma unroll
            for (int t = 0; t < TN; ++t) {
                const int col = colbase + t * 16 + r;
                sp += acc[mi][t][i] * aw_s[col];
                dp += acc[mi][t][i] * aw_d[col];
            }
#pragma unroll
            for (int m = 1; m < 16; m <<= 1) {
                sp += __shfl_xor(sp, m, 64);
                dp += __shfl_xor(dp, m, 64);
            }
            const int row = m0 + mi * 16 + q * 4 + i;
            if (r == 0 && row < M) {
                atomicAdd(&als[row * HS + hd], sp);
                atomicAdd(&ald[row * HS + hd], dp);
            }
        }
}

// ---------------- GAT aggregate, 2 waves per node, fp16 gather, 4-wide ----------------
__global__ __launch_bounds__(256) void k_agg4(const _Float16* __restrict__ hin,
                                              const float* __restrict__ als,
                                              const float* __restrict__ ald,
                                              const int* __restrict__ indptr,
                                              const int* __restrict__ esrc,
                                              const float* __restrict__ bias,
                                              const float* __restrict__ gamma,
                                              const float* __restrict__ beta,
                                              const float* __restrict__ mean,
                                              const float* __restrict__ var,
                                              unsigned short* __restrict__ phi,
                                              unsigned short* __restrict__ plo) {
    __shared__ float lacc[2][64][4];
    __shared__ float lsm[2][64];
    const int pair = threadIdx.x >> 7;          // node within block (0..1)
    const int wv   = (threadIdx.x >> 6) & 1;    // wave within pair
    const int lane = threadIdx.x & 63;
    const int n = blockIdx.x * 2 + pair;
    const int beg = indptr[n], end = indptr[n + 1];
    const int mid = beg + ((end - beg + 1) >> 1);
    const int e0 = wv ? mid : beg;
    const int e1 = wv ? end : mid;
    const int head = lane >> 4;
    const float aldn = ald[n * 4 + head];
    float4 acc = {0.f, 0.f, 0.f, 0.f};
    float sm = 0.f;
    const int c = lane * 4;
    int e = e0;
    for (; e + 3 < e1; e += 4) {       // 4 independent gather chains in flight
        const int s0 = esrc[e], s1 = esrc[e + 1], s2 = esrc[e + 2], s3 = esrc[e + 3];
        float v0 = als[s0 * 4 + head] + aldn;
        float v1 = als[s1 * 4 + head] + aldn;
        float v2 = als[s2 * 4 + head] + aldn;
        float v3 = als[s3 * 4 + head] + aldn;
        const v4h h0 = *(const v4h*)(hin + (size_t)s0 * 256 + c);
        const v4h h1 = *(const v4h*)(hin + (size_t)s1 * 256 + c);
        const v4h h2 = *(const v4h*)(hin + (size_t)s2 * 256 + c);
        const v4h h3 = *(const v4h*)(hin + (size_t)s3 * 256 + c);
        v0 = (v0 > 0.f) ? v0 : SLOPE * v0;
        v1 = (v1 > 0.f) ? v1 : SLOPE * v1;
        v2 = (v2 > 0.f) ? v2 : SLOPE * v2;
        v3 = (v3 > 0.f) ? v3 : SLOPE * v3;
        const float a0 = __expf(v0), a1 = __expf(v1), a2 = __expf(v2), a3 = __expf(v3);
        sm += (a0 + a1) + (a2 + a3);
        acc.x += a0 * (float)h0.x + a1 * (float)h1.x + a2 * (float)h2.x + a3 * (float)h3.x;
        acc.y += a0 * (float)h0.y + a1 * (float)h1.y + a2 * (float)h2.y + a3 * (float)h3.y;
        acc.z += a0 * (float)h0.z + a1 * (float)h1.z + a2 * (float)h2.z + a3 * (float)h3.z;
        acc.w += a0 * (float)h0.w + a1 * (float)h1.w + a2 * (float)h2.w + a3 * (float)h3.w;
    }
    for (; e < e1; ++e) {
        const int s0 = esrc[e];
        float v0 = als[s0 * 4 + head] + aldn;
        const v4h h0 = *(const v4h*)(hin + (size_t)s0 * 256 + c);
        v0 = (v0 > 0.f) ? v0 : SLOPE * v0;
        const float a0 = __expf(v0);
        sm += a0;
        acc.x += a0 * (float)h0.x; acc.y += a0 * (float)h0.y;
        acc.z += a0 * (float)h0.z; acc.w += a0 * (float)h0.w;
    }
    if (wv == 1) {
        lacc[pair][lane][0] = acc.x; lacc[pair][lane][1] = acc.y;
        lacc[pair][lane][2] = acc.z; lacc[pair][lane][3] = acc.w;
        lsm[pair][lane] = sm;
    }
    __syncthreads();
    if (wv == 0) {
        acc.x += lacc[pair][lane][0]; acc.y += lacc[pair][lane][1];
        acc.z += lacc[pair][lane][2]; acc.w += lacc[pair][lane][3];
        sm += lsm[pair][lane];
        const float invd = 1.f / (sm + 1e-16f);
        float y[4] = {acc.x * invd, acc.y * invd, acc.z * invd, acc.w * invd};
        ushort4 oh, ol;
        unsigned short* ph = &oh.x;
        unsigned short* pl = &ol.x;
#pragma unroll
        for (int i = 0; i < 4; ++i) {
            float t = y[i] + bias[c + i];
            t = (t - mean[c + i]) * rsqrtf(var[c + i] + EPS_BN) * gamma[c + i] + beta[c + i];
            t = fmaxf(t, 0.f);
            unsigned short h = f2bf(t);
            ph[i] = h;
            pl[i] = f2bf(t - bfu2f(h));
        }
        *(ushort4*)(phi + (size_t)n * 256 + c) = oh;
        *(ushort4*)(plo + (size_t)n * 256 + c) = ol;
    }
}

// ---------------- fused GAT aggregate (1 head) + bias + ReLU + pool-scatter ----------------
__global__ __launch_bounds__(256) void k_agg1(const _Float16* __restrict__ hin,
                                              const float* __restrict__ als,
                                              const float* __restrict__ ald,
                                              const int* __restrict__ indptr,
                                              const int* __restrict__ esrc,
                                              const float* __restrict__ bias,
                                              const int* __restrict__ batch,
                                              float* __restrict__ sums) {
    const int n = blockIdx.x * 4 + (threadIdx.x >> 6);
    const int lane = threadIdx.x & 63;
    const int beg = indptr[n], end = indptr[n + 1];
    const float aldn = ald[n];
    float acc = 0.f, sm = 0.f;
    int e = beg;
    for (; e + 3 < end; e += 4) {
        const int s0 = esrc[e], s1 = esrc[e + 1], s2 = esrc[e + 2], s3 = esrc[e + 3];
        float v0 = als[s0] + aldn;
        float v1 = als[s1] + aldn;
        float v2 = als[s2] + aldn;
        float v3 = als[s3] + aldn;
        const float h0 = (float)hin[(size_t)s0 * 64 + lane];
        const float h1 = (float)hin[(size_t)s1 * 64 + lane];
        const float h2 = (float)hin[(size_t)s2 * 64 + lane];
        const float h3 = (float)hin[(size_t)s3 * 64 + lane];
        v0 = (v0 > 0.f) ? v0 : SLOPE * v0;
        v1 = (v1 > 0.f) ? v1 : SLOPE * v1;
        v2 = (v2 > 0.f) ? v2 : SLOPE * v2;
        v3 = (v3 > 0.f) ? v3 : SLOPE * v3;
        const float a0 = __expf(v0), a1 = __expf(v1), a2 = __expf(v2), a3 = __expf(v3);
        sm += (a0 + a1) + (a2 + a3);
        acc += a0 * h0 + a1 * h1 + a2 * h2 + a3 * h3;
    }
    for (; e < end; ++e) {
        const int s0 = esrc[e];
        float v0 = als[s0] + aldn;
        const float h0 = (float)hin[(size_t)s0 * 64 + lane];
        v0 = (v0 > 0.f) ? v0 : SLOPE * v0;
        const float a0 = __expf(v0);
        sm += a0;
        acc += a0 * h0;
    }
    const float invd = 1.f / (sm + 1e-16f);
    const float val = fmaxf(acc * invd + bias[lane], 0.f);
    atomicAdd(&sums[batch[n] * 64 + lane], val);
}

__global__ void k_mlp(const float* __restrict__ sums, const int* __restrict__ gstart,
                      const float* __restrict__ w1, const float* __restrict__ b1,
                      const float* __restrict__ w2, const float* __restrict__ b2,
                      float* __restrict__ outp) {
    const int g = blockIdx.x;
    const int t = threadIdx.x;  // 32
    __shared__ float hid[32];
    const int cntn = gstart[g + 1] - gstart[g];
    const float inv = 1.f / (float)max(cntn, 1);
    float acc = b1[t];
    for (int c = 0; c < 64; ++c) acc += (sums[g * 64 + c] * inv) * w1[c * 32 + t];
    hid[t] = fmaxf(acc, 0.f);
    __syncthreads();
    if (t < N_CLASSES) {
        float o = b2[t];
        for (int k = 0; k < 32; ++k) o += hid[k] * w2[k * 5 + t];
        outp[g * 5 + t] = o;
    }
}

extern "C" void kernel_launch(void* const* d_in, const int* in_sizes, int n_in,
                              void* d_out, int out_size, void* d_ws, size_t ws_size,
                              hipStream_t stream) {
    const float* x        = (const float*)d_in[0];
    const int* edge_index = (const int*)d_in[1];
    const int* batch      = (const int*)d_in[2];
    const float* W1  = (const float*)d_in[3];
    const float* a1s = (const float*)d_in[4];
    const float* a1d = (const float*)d_in[5];
    const float* b1  = (const float*)d_in[6];
    const float* g1  = (const float*)d_in[7];
    const float* be1 = (const float*)d_in[8];
    const float* mu1 = (const float*)d_in[9];
    const float* va1 = (const float*)d_in[10];
    const float* W2  = (const float*)d_in[11];
    const float* a2s = (const float*)d_in[12];
    const float* a2d = (const float*)d_in[13];
    const float* b2  = (const float*)d_in[14];
    const float* g2  = (const float*)d_in[15];
    const float* be2 = (const float*)d_in[16];
    const float* mu2 = (const float*)d_in[17];
    const float* va2 = (const float*)d_in[18];
    const float* W3  = (const float*)d_in[19];
    const float* a3s = (const float*)d_in[20];
    const float* a3d = (const float*)d_in[21];
    const float* b3  = (const float*)d_in[22];
    const float* l1w = (const float*)d_in[23];
    const float* l1b = (const float*)d_in[24];
    const float* l2w = (const float*)d_in[25];
    const float* l2b = (const float*)d_in[26];
    float* out = (float*)d_out;

    char* w = (char*)d_ws;
    size_t off = 0;
    auto alloc = [&](size_t bytes) -> void* {
        void* p = w + off;
        off += (bytes + 255) & ~(size_t)255;
        return p;
    };
    unsigned short* xhi = (unsigned short*)alloc((size_t)N_NODES * 512 * 2);
    unsigned short* phi = xhi;                              // 20000*256 shorts
    unsigned short* plo = xhi + (size_t)N_NODES * 256;      // 20000*256 shorts
    _Float16* bufH  = (_Float16*)alloc((size_t)N_NODES * 256 * 2);  // GEMM1/2 out (fp16)
    _Float16* bufH3 = (_Float16*)alloc((size_t)N_NODES * 64 * 2);   // GEMM3 out (fp16)
    unsigned short* bt1h = (unsigned short*)alloc((size_t)512 * 256 * 2);
    unsigned short* bt1l = (unsigned short*)alloc((size_t)512 * 256 * 2);
    unsigned short* bt2h = (unsigned short*)alloc((size_t)256 * 256 * 2);
    unsigned short* bt2l = (unsigned short*)alloc((size_t)256 * 256 * 2);
    unsigned short* bt3h = (unsigned short*)alloc((size_t)256 * 64 * 2);
    unsigned short* bt3l = (unsigned short*)alloc((size_t)256 * 64 * 2);
    float* albase = (float*)alloc((size_t)ALZ * 4);  // als1,ald1,als2,ald2,als3,ald3
    float* als1 = albase;
    float* ald1 = albase + 80000;
    float* als2 = albase + 160000;
    float* ald2 = albase + 240000;
    float* als3 = albase + 320000;
    float* ald3 = albase + 340000;
    int* cnt      = (int*)alloc((size_t)N_NODES * 4);
    int* wptr     = (int*)alloc((size_t)N_NODES * 4);
    int* indptr   = (int*)alloc((size_t)(N_NODES + 1) * 4);
    int* esrc     = (int*)alloc((size_t)E_TOT * 4);
    int* gstart   = (int*)alloc((size_t)(N_GRAPHS + 1) * 4);
    float* sums   = (float*)alloc((size_t)N_GRAPHS * 64 * 4);

    // fused prep (weight splits, x->bf16, gstart, all zero-inits)
    const int PREP_IDS = SPQ + W1E + W2E + W3E + N_NODES + N_NODES + N_GRAPHS * 64 + ALZ;
    k_prep<<<(PREP_IDS + 255) / 256, 256, 0, stream>>>(x, xhi, W1, bt1h, bt1l, W2, bt2h, bt2l,
                                                       W3, bt3h, bt3l, batch, gstart, cnt, sums, albase);
    // CSR by dst (graph identical for all 3 layers)
    k_count<<<(E_TOT + 255) / 256, 256, 0, stream>>>(edge_index, cnt);
    k_scan<<<1, 1024, 0, stream>>>(cnt, indptr, wptr);
    k_scatter<<<(E_TOT + 255) / 256, 256, 0, stream>>>(edge_index, wptr, esrc);

    const int MB = (N_NODES + 63) / 64;  // 313 blocks of 64 rows

    // layer 1 (A = rne(x), 2 MFMA passes); logits fused into epilogue
    k_gemm_mfma<4, false, 512><<<dim3(MB, 2), 256, 0, stream>>>(xhi, (const unsigned short*)nullptr,
                                                                bt1h, bt1l, bufH, a1s, a1d, als1, ald1, 4,
                                                                N_NODES, 256);
    k_agg4<<<N_NODES / 2, 256, 0, stream>>>(bufH, als1, ald1, indptr, esrc, b1, g1, be1, mu1, va1, phi, plo);
    // layer 2 (A = hi/lo planes, 3 passes)
    k_gemm_mfma<4, true, 256><<<dim3(MB, 2), 256, 0, stream>>>(phi, plo, bt2h, bt2l, bufH, a2s, a2d, als2, ald2, 4,
                                                               N_NODES, 256);
    k_agg4<<<N_NODES / 2, 256, 0, stream>>>(bufH, als2, ald2, indptr, esrc, b2, g2, be2, mu2, va2, phi, plo);
    // layer 3
    k_gemm_mfma<2, true, 256><<<dim3(MB, 1), 256, 0, stream>>>(phi, plo, bt3h, bt3l, bufH3, a3s, a3d, als3, ald3, 1,
                                                               N_NODES, 64);
    k_agg1<<<N_NODES / 4, 256, 0, stream>>>(bufH3, als3, ald3, indptr, esrc, b3, batch, sums);
    // readout
    k_mlp<<<N_GRAPHS, 32, 0, stream>>>(sums, gstart, l1w, l1b, l2w, l2b, out);
}

// Round 14
// 351.706 us; speedup vs baseline: 1.0737x; 1.0425x over previous
//
#include <hip/hip_runtime.h>

#define N_NODES 20000
#define N_EDGES 320000
#define E_TOT   340000   // edges + self loops
#define N_GRAPHS 64
#define N_CLASSES 5
#define SLOPE 0.2f
#define EPS_BN 1e-5f

typedef short v8s __attribute__((ext_vector_type(8)));    // 8 bf16 (4 VGPRs)
typedef float v4f __attribute__((ext_vector_type(4)));    // 4 f32 acc
typedef _Float16 v4h __attribute__((ext_vector_type(4))); // 4 fp16 (8 B)

__device__ __forceinline__ float bfu2f(unsigned short u) {
    return __uint_as_float(((unsigned int)u) << 16);
}
__device__ __forceinline__ unsigned short f2bf(float f) {  // round-to-nearest-even
    unsigned int u = __float_as_uint(f);
    return (unsigned short)((u + 0x7FFF + ((u >> 16) & 1)) >> 16);
}

// ---------------- fused prep: weight splits + x->bf16 + zeros + gstart ----------------
#define SPQ (N_NODES * 512 / 4)
#define W1E (512 * 256)
#define W2E (256 * 256)
#define W3E (256 * 64)
#define ALZ (80000 * 4 + 20000 * 2)   // als1,ald1,als2,ald2 (4x80000) + als3,ald3 (2x20000)

__global__ __launch_bounds__(256) void k_prep(const float* __restrict__ x,
                                              unsigned short* __restrict__ xhi,
                                              const float* __restrict__ W1,
                                              unsigned short* __restrict__ bt1h,
                                              const float* __restrict__ W2,
                                              unsigned short* __restrict__ bt2h, unsigned short* __restrict__ bt2l,
                                              const float* __restrict__ W3,
                                              unsigned short* __restrict__ bt3h, unsigned short* __restrict__ bt3l,
                                              const int* __restrict__ batch, int* __restrict__ gstart,
                                              int* __restrict__ cnt, float* __restrict__ sums,
                                              float* __restrict__ albase) {
    int id = blockIdx.x * 256 + threadIdx.x;
    if (id < SPQ) {
        const float4 v = *(const float4*)(x + (size_t)id * 4);
        ushort4 h;
        h.x = f2bf(v.x); h.y = f2bf(v.y); h.z = f2bf(v.z); h.w = f2bf(v.w);
        *(ushort4*)(xhi + (size_t)id * 4) = h;
        return;
    }
    id -= SPQ;
    if (id < W1E) {   // W1: single rne-bf16 plane (lo dropped; layer-1 A already rne)
        const int K = 512, N = 256;
        int n = id / K, k = id - n * K;
        bt1h[id] = f2bf(W1[(size_t)k * N + n]);
        return;
    }
    id -= W1E;
    if (id < W2E) {
        const int K = 256, N = 256;
        int n = id / K, k = id - n * K;
        float f = W2[(size_t)k * N + n];
        unsigned short h = f2bf(f);
        bt2h[id] = h;
        bt2l[id] = f2bf(f - bfu2f(h));
        return;
    }
    id -= W2E;
    if (id < W3E) {
        const int K = 256, N = 64;
        int n = id / K, k = id - n * K;
        float f = W3[(size_t)k * N + n];
        unsigned short h = f2bf(f);
        bt3h[id] = h;
        bt3l[id] = f2bf(f - bfu2f(h));
        return;
    }
    id -= W3E;
    if (id < N_NODES) {
        int i = id;
        int b = batch[i];
        if (i == 0) {
            for (int g = 0; g <= b; ++g) gstart[g] = 0;
        } else {
            int p = batch[i - 1];
            for (int g = p + 1; g <= b; ++g) gstart[g] = i;
        }
        if (i == N_NODES - 1) {
            for (int g = b + 1; g <= N_GRAPHS; ++g) gstart[g] = N_NODES;
        }
        return;
    }
    id -= N_NODES;
    if (id < N_NODES) { cnt[id] = 0; return; }
    id -= N_NODES;
    if (id < N_GRAPHS * 64) { sums[id] = 0.f; return; }
    id -= N_GRAPHS * 64;
    if (id < ALZ) albase[id] = 0.f;
}

// ---------------- CSR build ----------------
__global__ void k_count(const int* __restrict__ ei, int* __restrict__ cnt) {
    int e = blockIdx.x * 256 + threadIdx.x;
    if (e >= E_TOT) return;
    int d = (e < N_EDGES) ? ei[N_EDGES + e] : (e - N_EDGES);
    atomicAdd(&cnt[d], 1);
}

__global__ __launch_bounds__(1024) void k_scan(const int* __restrict__ cnt,
                                               int* __restrict__ indptr,
                                               int* __restrict__ wptr) {
    __shared__ int smem[1024];
    const int t = threadIdx.x;
    const int per = (N_NODES + 1023) / 1024;  // 20
    const int i0 = t * per;
    int lsum = 0;
    for (int j = 0; j < per; ++j) {
        int i = i0 + j;
        if (i < N_NODES) lsum += cnt[i];
    }
    smem[t] = lsum;
    __syncthreads();
    for (int off = 1; off < 1024; off <<= 1) {
        int v = (t >= off) ? smem[t - off] : 0;
        __syncthreads();
        smem[t] += v;
        __syncthreads();
    }
    int run = smem[t] - lsum;  // exclusive prefix
    for (int j = 0; j < per; ++j) {
        int i = i0 + j;
        if (i < N_NODES) {
            indptr[i] = run;
            wptr[i] = run;
            run += cnt[i];
        }
    }
    if (t == 1023) indptr[N_NODES] = E_TOT;
}

__global__ void k_scatter(const int* __restrict__ ei, int* __restrict__ wptr,
                          int* __restrict__ esrc) {
    int e = blockIdx.x * 256 + threadIdx.x;
    if (e >= E_TOT) return;
    int s, d;
    if (e < N_EDGES) { s = ei[e]; d = ei[N_EDGES + e]; }
    else             { s = d = e - N_EDGES; }
    int pos = atomicAdd(&wptr[d], 1);
    esrc[pos] = s;
}

// ---------------- MFMA GEMM, 64-row blocks, coalesced LDS-staged B, register
// double-buffer, single-plane A, optional split B (SPLITB), fp16 C, fused logits.
template <int TN, bool SPLITB, int KK>
__global__ __launch_bounds__(256) void k_gemm_mfma(const unsigned short* __restrict__ Ahi,
                                                   const unsigned short* __restrict__ Bth,
                                                   const unsigned short* __restrict__ Btl,
                                                   _Float16* __restrict__ H,
                                                   const float* __restrict__ aw_s,
                                                   const float* __restrict__ aw_d,
                                                   float* __restrict__ als,
                                                   float* __restrict__ ald,
                                                   int HS,          // head stride of als/ald (4 or 1)
                                                   int M, int N) {
    constexpr int NTB = 2 * TN;             // n-tiles per block
    constexpr int NFRAG = 2 * NTB * 64;     // fragments per plane per K-chunk (2 ksteps)
    constexpr int NITER = NFRAG / 256;      // staging iterations per thread
    constexpr int LDSW = NFRAG * 8 + (NFRAG >> 4) * 8;  // shorts, with skew padding
    __shared__ short lbh[LDSW];
    __shared__ short lbl[SPLITB ? LDSW : 16];
    const int tid = threadIdx.x;
    const int wave = tid >> 6, lane = tid & 63;
    const int wr = wave >> 1, wc = wave & 1;   // 2x2 wave grid
    const int q = lane >> 4, r = lane & 15;
    const int m0 = blockIdx.x * 64 + wr * 32;
    const int n0 = blockIdx.y * (NTB * 16);
    size_t abase[2];
#pragma unroll
    for (int mi = 0; mi < 2; ++mi) {
        int ar = m0 + mi * 16 + r;
        if (ar >= M) ar = M - 1;               // clamp; stores guarded
        abase[mi] = (size_t)ar * KK + q * 8;
    }
    // per-thread staging addresses (coalesced: qq/ss in low tid bits) + LDS offsets
    size_t gaddr[NITER];
    int loff[NITER];
#pragma unroll
    for (int j = 0; j < NITER; ++j) {
        const int f = tid + j * 256;
        const int qq = f & 3;
        const int ss = (f >> 2) & 1;
        const int rr = (f >> 3) & 15;
        const int tt = f >> 7;
        gaddr[j] = (size_t)(n0 + tt * 16 + rr) * KK + ss * 32 + qq * 8;
        const int fi = (ss * NTB + tt) * 64 + qq * 16 + rr;
        loff[j] = fi * 8 + (fi >> 4) * 8;   // 16B skew per 16 frags
    }
    v4f acc[2][TN];
#pragma unroll
    for (int mi = 0; mi < 2; ++mi)
#pragma unroll
        for (int t = 0; t < TN; ++t) acc[mi][t] = (v4f){0.f, 0.f, 0.f, 0.f};

    // preload chunk 0 into registers
    v8s ch[NITER], cl[NITER];
#pragma unroll
    for (int j = 0; j < NITER; ++j) {
        ch[j] = *(const v8s*)(Bth + gaddr[j]);
        if constexpr (SPLITB) cl[j] = *(const v8s*)(Btl + gaddr[j]);
    }

#pragma unroll
    for (int kc = 0; kc < KK; kc += 64) {
        __syncthreads();
#pragma unroll
        for (int j = 0; j < NITER; ++j) {
            *(v8s*)&lbh[loff[j]] = ch[j];
            if constexpr (SPLITB) *(v8s*)&lbl[loff[j]] = cl[j];
        }
        __syncthreads();
        if (kc + 64 < KK) {     // prefetch next chunk; overlaps with MFMA below
#pragma unroll
            for (int j = 0; j < NITER; ++j) {
                ch[j] = *(const v8s*)(Bth + gaddr[j] + kc + 64);
                if constexpr (SPLITB) cl[j] = *(const v8s*)(Btl + gaddr[j] + kc + 64);
            }
        }
#pragma unroll
        for (int ss = 0; ss < 2; ++ss) {
            v8s ah[2];
#pragma unroll
            for (int mi = 0; mi < 2; ++mi)
                ah[mi] = *(const v8s*)(Ahi + abase[mi] + kc + ss * 32);
#pragma unroll
            for (int t = 0; t < TN; ++t) {
                const int fib = (ss * NTB + wc * TN + t) * 4 + q;
                const int off = (fib * 16 + r) * 8 + fib * 8;   // matches staging skew
                const v8s bh = *(const v8s*)&lbh[off];
#pragma unroll
                for (int mi = 0; mi < 2; ++mi)
                    acc[mi][t] = __builtin_amdgcn_mfma_f32_16x16x32_bf16(ah[mi], bh, acc[mi][t], 0, 0, 0);
                if constexpr (SPLITB) {
                    const v8s bl = *(const v8s*)&lbl[off];
#pragma unroll
                    for (int mi = 0; mi < 2; ++mi)
                        acc[mi][t] = __builtin_amdgcn_mfma_f32_16x16x32_bf16(ah[mi], bl, acc[mi][t], 0, 0, 0);
                }
            }
        }
    }
    // C/D layout: col = lane&15, row = quad*4 + reg; store fp16
#pragma unroll
    for (int mi = 0; mi < 2; ++mi)
#pragma unroll
        for (int t = 0; t < TN; ++t)
#pragma unroll
            for (int i = 0; i < 4; ++i) {
                const int row = m0 + mi * 16 + q * 4 + i;
                if (row < M) H[(size_t)row * N + n0 + (wc * TN + t) * 16 + r] = (_Float16)acc[mi][t][i];
            }
    // fused attention-logit partials: each wave's columns lie in one head
    const int colbase = n0 + wc * TN * 16;
    const int hd = colbase >> 6;
#pragma unroll
    for (int mi = 0; mi < 2; ++mi)
#pragma unroll
        for (int i = 0; i < 4; ++i) {
            float sp = 0.f, dp = 0.f;
#pragma unroll
            for (int t = 0; t < TN; ++t) {
                const int col = colbase + t * 16 + r;
                sp += acc[mi][t][i] * aw_s[col];
                dp += acc[mi][t][i] * aw_d[col];
            }
#pragma unroll
            for (int m = 1; m < 16; m <<= 1) {
                sp += __shfl_xor(sp, m, 64);
                dp += __shfl_xor(dp, m, 64);
            }
            const int row = m0 + mi * 16 + q * 4 + i;
            if (r == 0 && row < M) {
                atomicAdd(&als[row * HS + hd], sp);
                atomicAdd(&ald[row * HS + hd], dp);
            }
        }
}

// ---------------- GAT aggregate, 2 waves per node, fp16 gather, 4-wide ----------------
// Epilogue writes a single rne-bf16 plane (next GEMM uses single-plane A).
__global__ __launch_bounds__(256) void k_agg4(const _Float16* __restrict__ hin,
                                              const float* __restrict__ als,
                                              const float* __restrict__ ald,
                                              const int* __restrict__ indptr,
                                              const int* __restrict__ esrc,
                                              const float* __restrict__ bias,
                                              const float* __restrict__ gamma,
                                              const float* __restrict__ beta,
                                              const float* __restrict__ mean,
                                              const float* __restrict__ var,
                                              unsigned short* __restrict__ phi) {
    __shared__ float lacc[2][64][4];
    __shared__ float lsm[2][64];
    const int pair = threadIdx.x >> 7;          // node within block (0..1)
    const int wv   = (threadIdx.x >> 6) & 1;    // wave within pair
    const int lane = threadIdx.x & 63;
    const int n = blockIdx.x * 2 + pair;
    const int beg = indptr[n], end = indptr[n + 1];
    const int mid = beg + ((end - beg + 1) >> 1);
    const int e0 = wv ? mid : beg;
    const int e1 = wv ? end : mid;
    const int head = lane >> 4;
    const float aldn = ald[n * 4 + head];
    float4 acc = {0.f, 0.f, 0.f, 0.f};
    float sm = 0.f;
    const int c = lane * 4;
    int e = e0;
    for (; e + 3 < e1; e += 4) {       // 4 independent gather chains in flight
        const int s0 = esrc[e], s1 = esrc[e + 1], s2 = esrc[e + 2], s3 = esrc[e + 3];
        float v0 = als[s0 * 4 + head] + aldn;
        float v1 = als[s1 * 4 + head] + aldn;
        float v2 = als[s2 * 4 + head] + aldn;
        float v3 = als[s3 * 4 + head] + aldn;
        const v4h h0 = *(const v4h*)(hin + (size_t)s0 * 256 + c);
        const v4h h1 = *(const v4h*)(hin + (size_t)s1 * 256 + c);
        const v4h h2 = *(const v4h*)(hin + (size_t)s2 * 256 + c);
        const v4h h3 = *(const v4h*)(hin + (size_t)s3 * 256 + c);
        v0 = (v0 > 0.f) ? v0 : SLOPE * v0;
        v1 = (v1 > 0.f) ? v1 : SLOPE * v1;
        v2 = (v2 > 0.f) ? v2 : SLOPE * v2;
        v3 = (v3 > 0.f) ? v3 : SLOPE * v3;
        const float a0 = __expf(v0), a1 = __expf(v1), a2 = __expf(v2), a3 = __expf(v3);
        sm += (a0 + a1) + (a2 + a3);
        acc.x += a0 * (float)h0.x + a1 * (float)h1.x + a2 * (float)h2.x + a3 * (float)h3.x;
        acc.y += a0 * (float)h0.y + a1 * (float)h1.y + a2 * (float)h2.y + a3 * (float)h3.y;
        acc.z += a0 * (float)h0.z + a1 * (float)h1.z + a2 * (float)h2.z + a3 * (float)h3.z;
        acc.w += a0 * (float)h0.w + a1 * (float)h1.w + a2 * (float)h2.w + a3 * (float)h3.w;
    }
    for (; e < e1; ++e) {
        const int s0 = esrc[e];
        float v0 = als[s0 * 4 + head] + aldn;
        const v4h h0 = *(const v4h*)(hin + (size_t)s0 * 256 + c);
        v0 = (v0 > 0.f) ? v0 : SLOPE * v0;
        const float a0 = __expf(v0);
        sm += a0;
        acc.x += a0 * (float)h0.x; acc.y += a0 * (float)h0.y;
        acc.z += a0 * (float)h0.z; acc.w += a0 * (float)h0.w;
    }
    if (wv == 1) {
        lacc[pair][lane][0] = acc.x; lacc[pair][lane][1] = acc.y;
        lacc[pair][lane][2] = acc.z; lacc[pair][lane][3] = acc.w;
        lsm[pair][lane] = sm;
    }
    __syncthreads();
    if (wv == 0) {
        acc.x += lacc[pair][lane][0]; acc.y += lacc[pair][lane][1];
        acc.z += lacc[pair][lane][2]; acc.w += lacc[pair][lane][3];
        sm += lsm[pair][lane];
        const float invd = 1.f / (sm + 1e-16f);
        float y[4] = {acc.x * invd, acc.y * invd, acc.z * invd, acc.w * invd};
        ushort4 oh;
        unsigned short* ph = &oh.x;
#pragma unroll
        for (int i = 0; i < 4; ++i) {
            float t = y[i] + bias[c + i];
            t = (t - mean[c + i]) * rsqrtf(var[c + i] + EPS_BN) * gamma[c + i] + beta[c + i];
            t = fmaxf(t, 0.f);
            ph[i] = f2bf(t);
        }
        *(ushort4*)(phi + (size_t)n * 256 + c) = oh;
    }
}

// ---------------- fused GAT aggregate (1 head) + bias + ReLU + pool-scatter ----------------
__global__ __launch_bounds__(256) void k_agg1(const _Float16* __restrict__ hin,
                                              const float* __restrict__ als,
                                              const float* __restrict__ ald,
                                              const int* __restrict__ indptr,
                                              const int* __restrict__ esrc,
                                              const float* __restrict__ bias,
                                              const int* __restrict__ batch,
                                              float* __restrict__ sums) {
    const int n = blockIdx.x * 4 + (threadIdx.x >> 6);
    const int lane = threadIdx.x & 63;
    const int beg = indptr[n], end = indptr[n + 1];
    const float aldn = ald[n];
    float acc = 0.f, sm = 0.f;
    int e = beg;
    for (; e + 3 < end; e += 4) {
        const int s0 = esrc[e], s1 = esrc[e + 1], s2 = esrc[e + 2], s3 = esrc[e + 3];
        float v0 = als[s0] + aldn;
        float v1 = als[s1] + aldn;
        float v2 = als[s2] + aldn;
        float v3 = als[s3] + aldn;
        const float h0 = (float)hin[(size_t)s0 * 64 + lane];
        const float h1 = (float)hin[(size_t)s1 * 64 + lane];
        const float h2 = (float)hin[(size_t)s2 * 64 + lane];
        const float h3 = (float)hin[(size_t)s3 * 64 + lane];
        v0 = (v0 > 0.f) ? v0 : SLOPE * v0;
        v1 = (v1 > 0.f) ? v1 : SLOPE * v1;
        v2 = (v2 > 0.f) ? v2 : SLOPE * v2;
        v3 = (v3 > 0.f) ? v3 : SLOPE * v3;
        const float a0 = __expf(v0), a1 = __expf(v1), a2 = __expf(v2), a3 = __expf(v3);
        sm += (a0 + a1) + (a2 + a3);
        acc += a0 * h0 + a1 * h1 + a2 * h2 + a3 * h3;
    }
    for (; e < end; ++e) {
        const int s0 = esrc[e];
        float v0 = als[s0] + aldn;
        const float h0 = (float)hin[(size_t)s0 * 64 + lane];
        v0 = (v0 > 0.f) ? v0 : SLOPE * v0;
        const float a0 = __expf(v0);
        sm += a0;
        acc += a0 * h0;
    }
    const float invd = 1.f / (sm + 1e-16f);
    const float val = fmaxf(acc * invd + bias[lane], 0.f);
    atomicAdd(&sums[batch[n] * 64 + lane], val);
}

__global__ void k_mlp(const float* __restrict__ sums, const int* __restrict__ gstart,
                      const float* __restrict__ w1, const float* __restrict__ b1,
                      const float* __restrict__ w2, const float* __restrict__ b2,
                      float* __restrict__ outp) {
    const int g = blockIdx.x;
    const int t = threadIdx.x;  // 32
    __shared__ float hid[32];
    const int cntn = gstart[g + 1] - gstart[g];
    const float inv = 1.f / (float)max(cntn, 1);
    float acc = b1[t];
    for (int c = 0; c < 64; ++c) acc += (sums[g * 64 + c] * inv) * w1[c * 32 + t];
    hid[t] = fmaxf(acc, 0.f);
    __syncthreads();
    if (t < N_CLASSES) {
        float o = b2[t];
        for (int k = 0; k < 32; ++k) o += hid[k] * w2[k * 5 + t];
        outp[g * 5 + t] = o;
    }
}

extern "C" void kernel_launch(void* const* d_in, const int* in_sizes, int n_in,
                              void* d_out, int out_size, void* d_ws, size_t ws_size,
                              hipStream_t stream) {
    const float* x        = (const float*)d_in[0];
    const int* edge_index = (const int*)d_in[1];
    const int* batch      = (const int*)d_in[2];
    const float* W1  = (const float*)d_in[3];
    const float* a1s = (const float*)d_in[4];
    const float* a1d = (const float*)d_in[5];
    const float* b1  = (const float*)d_in[6];
    const float* g1  = (const float*)d_in[7];
    const float* be1 = (const float*)d_in[8];
    const float* mu1 = (const float*)d_in[9];
    const float* va1 = (const float*)d_in[10];
    const float* W2  = (const float*)d_in[11];
    const float* a2s = (const float*)d_in[12];
    const float* a2d = (const float*)d_in[13];
    const float* b2  = (const float*)d_in[14];
    const float* g2  = (const float*)d_in[15];
    const float* be2 = (const float*)d_in[16];
    const float* mu2 = (const float*)d_in[17];
    const float* va2 = (const float*)d_in[18];
    const float* W3  = (const float*)d_in[19];
    const float* a3s = (const float*)d_in[20];
    const float* a3d = (const float*)d_in[21];
    const float* b3  = (const float*)d_in[22];
    const float* l1w = (const float*)d_in[23];
    const float* l1b = (const float*)d_in[24];
    const float* l2w = (const float*)d_in[25];
    const float* l2b = (const float*)d_in[26];
    float* out = (float*)d_out;

    char* w = (char*)d_ws;
    size_t off = 0;
    auto alloc = [&](size_t bytes) -> void* {
        void* p = w + off;
        off += (bytes + 255) & ~(size_t)255;
        return p;
    };
    unsigned short* xhi = (unsigned short*)alloc((size_t)N_NODES * 512 * 2);
    unsigned short* phi = xhi;                              // 20000*256 shorts (activation plane)
    _Float16* bufH  = (_Float16*)alloc((size_t)N_NODES * 256 * 2);  // GEMM1/2 out (fp16)
    _Float16* bufH3 = (_Float16*)alloc((size_t)N_NODES * 64 * 2);   // GEMM3 out (fp16)
    unsigned short* bt1h = (unsigned short*)alloc((size_t)512 * 256 * 2);
    unsigned short* bt2h = (unsigned short*)alloc((size_t)256 * 256 * 2);
    unsigned short* bt2l = (unsigned short*)alloc((size_t)256 * 256 * 2);
    unsigned short* bt3h = (unsigned short*)alloc((size_t)256 * 64 * 2);
    unsigned short* bt3l = (unsigned short*)alloc((size_t)256 * 64 * 2);
    float* albase = (float*)alloc((size_t)ALZ * 4);  // als1,ald1,als2,ald2,als3,ald3
    float* als1 = albase;
    float* ald1 = albase + 80000;
    float* als2 = albase + 160000;
    float* ald2 = albase + 240000;
    float* als3 = albase + 320000;
    float* ald3 = albase + 340000;
    int* cnt      = (int*)alloc((size_t)N_NODES * 4);
    int* wptr     = (int*)alloc((size_t)N_NODES * 4);
    int* indptr   = (int*)alloc((size_t)(N_NODES + 1) * 4);
    int* esrc     = (int*)alloc((size_t)E_TOT * 4);
    int* gstart   = (int*)alloc((size_t)(N_GRAPHS + 1) * 4);
    float* sums   = (float*)alloc((size_t)N_GRAPHS * 64 * 4);

    // fused prep (weight splits, x->bf16, gstart, all zero-inits)
    const int PREP_IDS = SPQ + W1E + W2E + W3E + N_NODES + N_NODES + N_GRAPHS * 64 + ALZ;
    k_prep<<<(PREP_IDS + 255) / 256, 256, 0, stream>>>(x, xhi, W1, bt1h, W2, bt2h, bt2l,
                                                       W3, bt3h, bt3l, batch, gstart, cnt, sums, albase);
    // CSR by dst (graph identical for all 3 layers)
    k_count<<<(E_TOT + 255) / 256, 256, 0, stream>>>(edge_index, cnt);
    k_scan<<<1, 1024, 0, stream>>>(cnt, indptr, wptr);
    k_scatter<<<(E_TOT + 255) / 256, 256, 0, stream>>>(edge_index, wptr, esrc);

    const int MB = (N_NODES + 63) / 64;  // 313 blocks of 64 rows

    // layer 1: A = rne(x), B = rne(W1) (single plane, 1 MFMA pass); logits fused
    k_gemm_mfma<4, false, 512><<<dim3(MB, 2), 256, 0, stream>>>(xhi, bt1h, bt1h, bufH,
                                                                a1s, a1d, als1, ald1, 4,
                                                                N_NODES, 256);
    k_agg4<<<N_NODES / 2, 256, 0, stream>>>(bufH, als1, ald1, indptr, esrc, b1, g1, be1, mu1, va1, phi);
    // layer 2: A = rne(act), B split hi/lo (2 passes)
    k_gemm_mfma<4, true, 256><<<dim3(MB, 2), 256, 0, stream>>>(phi, bt2h, bt2l, bufH,
                                                               a2s, a2d, als2, ald2, 4,
                                                               N_NODES, 256);
    k_agg4<<<N_NODES / 2, 256, 0, stream>>>(bufH, als2, ald2, indptr, esrc, b2, g2, be2, mu2, va2, phi);
    // layer 3
    k_gemm_mfma<2, true, 256><<<dim3(MB, 1), 256, 0, stream>>>(phi, bt3h, bt3l, bufH3,
                                                               a3s, a3d, als3, ald3, 1,
                                                               N_NODES, 64);
    k_agg1<<<N_NODES / 4, 256, 0, stream>>>(bufH3, als3, ald3, indptr, esrc, b3, batch, sums);
    // readout
    k_mlp<<<N_GRAPHS, 32, 0, stream>>>(sums, gstart, l1w, l1b, l2w, l2b, out);
}

// Round 15
// 351.475 us; speedup vs baseline: 1.0744x; 1.0007x over previous
//
#include <hip/hip_runtime.h>

#define N_NODES 20000
#define N_EDGES 320000
#define E_TOT   340000   // edges + self loops
#define N_GRAPHS 64
#define N_CLASSES 5
#define SLOPE 0.2f
#define EPS_BN 1e-5f

typedef _Float16 v8h __attribute__((ext_vector_type(8)));  // 8 fp16 (4 VGPRs) MFMA operand
typedef float v4f __attribute__((ext_vector_type(4)));     // 4 f32 acc
typedef _Float16 v4h __attribute__((ext_vector_type(4)));  // 4 fp16 (8 B)

// ---------------- fused prep: weight transpose-casts + x->fp16 + zeros + gstart ----------------
#define SPQ (N_NODES * 512 / 4)
#define W1E (512 * 256)
#define W2E (256 * 256)
#define W3E (256 * 64)
#define ALZ (80000 * 4 + 20000 * 2)   // als1,ald1,als2,ald2 (4x80000) + als3,ald3 (2x20000)

__global__ __launch_bounds__(256) void k_prep(const float* __restrict__ x,
                                              _Float16* __restrict__ xh,
                                              const float* __restrict__ W1, _Float16* __restrict__ bt1,
                                              const float* __restrict__ W2, _Float16* __restrict__ bt2,
                                              const float* __restrict__ W3, _Float16* __restrict__ bt3,
                                              const int* __restrict__ batch, int* __restrict__ gstart,
                                              int* __restrict__ cnt, float* __restrict__ sums,
                                              float* __restrict__ albase) {
    int id = blockIdx.x * 256 + threadIdx.x;
    if (id < SPQ) {
        const float4 v = *(const float4*)(x + (size_t)id * 4);
        v4h h;
        h.x = (_Float16)v.x; h.y = (_Float16)v.y; h.z = (_Float16)v.z; h.w = (_Float16)v.w;
        *(v4h*)(xh + (size_t)id * 4) = h;
        return;
    }
    id -= SPQ;
    if (id < W1E) {
        const int K = 512, N = 256;
        int n = id / K, k = id - n * K;
        bt1[id] = (_Float16)W1[(size_t)k * N + n];
        return;
    }
    id -= W1E;
    if (id < W2E) {
        const int K = 256, N = 256;
        int n = id / K, k = id - n * K;
        bt2[id] = (_Float16)W2[(size_t)k * N + n];
        return;
    }
    id -= W2E;
    if (id < W3E) {
        const int K = 256, N = 64;
        int n = id / K, k = id - n * K;
        bt3[id] = (_Float16)W3[(size_t)k * N + n];
        return;
    }
    id -= W3E;
    if (id < N_NODES) {
        int i = id;
        int b = batch[i];
        if (i == 0) {
            for (int g = 0; g <= b; ++g) gstart[g] = 0;
        } else {
            int p = batch[i - 1];
            for (int g = p + 1; g <= b; ++g) gstart[g] = i;
        }
        if (i == N_NODES - 1) {
            for (int g = b + 1; g <= N_GRAPHS; ++g) gstart[g] = N_NODES;
        }
        return;
    }
    id -= N_NODES;
    if (id < N_NODES) { cnt[id] = 0; return; }
    id -= N_NODES;
    if (id < N_GRAPHS * 64) { sums[id] = 0.f; return; }
    id -= N_GRAPHS * 64;
    if (id < ALZ) albase[id] = 0.f;
}

// ---------------- CSR build ----------------
__global__ void k_count(const int* __restrict__ ei, int* __restrict__ cnt) {
    int e = blockIdx.x * 256 + threadIdx.x;
    if (e >= E_TOT) return;
    int d = (e < N_EDGES) ? ei[N_EDGES + e] : (e - N_EDGES);
    atomicAdd(&cnt[d], 1);
}

__global__ __launch_bounds__(1024) void k_scan(const int* __restrict__ cnt,
                                               int* __restrict__ indptr,
                                               int* __restrict__ wptr) {
    __shared__ int smem[1024];
    const int t = threadIdx.x;
    const int per = (N_NODES + 1023) / 1024;  // 20
    const int i0 = t * per;
    int lsum = 0;
    for (int j = 0; j < per; ++j) {
        int i = i0 + j;
        if (i < N_NODES) lsum += cnt[i];
    }
    smem[t] = lsum;
    __syncthreads();
    for (int off = 1; off < 1024; off <<= 1) {
        int v = (t >= off) ? smem[t - off] : 0;
        __syncthreads();
        smem[t] += v;
        __syncthreads();
    }
    int run = smem[t] - lsum;  // exclusive prefix
    for (int j = 0; j < per; ++j) {
        int i = i0 + j;
        if (i < N_NODES) {
            indptr[i] = run;
            wptr[i] = run;
            run += cnt[i];
        }
    }
    if (t == 1023) indptr[N_NODES] = E_TOT;
}

__global__ void k_scatter(const int* __restrict__ ei, int* __restrict__ wptr,
                          int* __restrict__ esrc) {
    int e = blockIdx.x * 256 + threadIdx.x;
    if (e >= E_TOT) return;
    int s, d;
    if (e < N_EDGES) { s = ei[e]; d = ei[N_EDGES + e]; }
    else             { s = d = e - N_EDGES; }
    int pos = atomicAdd(&wptr[d], 1);
    esrc[pos] = s;
}

// ---------------- f16 MFMA GEMM, 64-row blocks, coalesced LDS-staged B,
// register double-buffer, single fp16 planes, fp16 C, fused logits ----------------
template <int TN, int KK>
__global__ __launch_bounds__(256) void k_gemm_mfma(const _Float16* __restrict__ A,
                                                   const _Float16* __restrict__ Bt,
                                                   _Float16* __restrict__ H,
                                                   const float* __restrict__ aw_s,
                                                   const float* __restrict__ aw_d,
                                                   float* __restrict__ als,
                                                   float* __restrict__ ald,
                                                   int HS,          // head stride of als/ald (4 or 1)
                                                   int M, int N) {
    constexpr int NTB = 2 * TN;             // n-tiles per block
    constexpr int NFRAG = 2 * NTB * 64;     // fragments per K-chunk (2 ksteps)
    constexpr int NITER = NFRAG / 256;      // staging iterations per thread
    constexpr int LDSW = NFRAG * 8 + (NFRAG >> 4) * 8;  // halfs, with skew padding
    __shared__ _Float16 lbh[LDSW];
    const int tid = threadIdx.x;
    const int wave = tid >> 6, lane = tid & 63;
    const int wr = wave >> 1, wc = wave & 1;   // 2x2 wave grid
    const int q = lane >> 4, r = lane & 15;
    const int m0 = blockIdx.x * 64 + wr * 32;
    const int n0 = blockIdx.y * (NTB * 16);
    size_t abase[2];
#pragma unroll
    for (int mi = 0; mi < 2; ++mi) {
        int ar = m0 + mi * 16 + r;
        if (ar >= M) ar = M - 1;               // clamp; stores guarded
        abase[mi] = (size_t)ar * KK + q * 8;
    }
    // per-thread staging addresses (coalesced: qq/ss in low tid bits) + LDS offsets
    size_t gaddr[NITER];
    int loff[NITER];
#pragma unroll
    for (int j = 0; j < NITER; ++j) {
        const int f = tid + j * 256;
        const int qq = f & 3;
        const int ss = (f >> 2) & 1;
        const int rr = (f >> 3) & 15;
        const int tt = f >> 7;
        gaddr[j] = (size_t)(n0 + tt * 16 + rr) * KK + ss * 32 + qq * 8;
        const int fi = (ss * NTB + tt) * 64 + qq * 16 + rr;
        loff[j] = fi * 8 + (fi >> 4) * 8;   // 16B skew per 16 frags
    }
    v4f acc[2][TN];
#pragma unroll
    for (int mi = 0; mi < 2; ++mi)
#pragma unroll
        for (int t = 0; t < TN; ++t) acc[mi][t] = (v4f){0.f, 0.f, 0.f, 0.f};

    // preload chunk 0 into registers
    v8h ch[NITER];
#pragma unroll
    for (int j = 0; j < NITER; ++j) ch[j] = *(const v8h*)(Bt + gaddr[j]);

#pragma unroll
    for (int kc = 0; kc < KK; kc += 64) {
        __syncthreads();
#pragma unroll
        for (int j = 0; j < NITER; ++j) *(v8h*)&lbh[loff[j]] = ch[j];
        __syncthreads();
        if (kc + 64 < KK) {     // prefetch next chunk; overlaps with MFMA below
#pragma unroll
            for (int j = 0; j < NITER; ++j) ch[j] = *(const v8h*)(Bt + gaddr[j] + kc + 64);
        }
#pragma unroll
        for (int ss = 0; ss < 2; ++ss) {
            v8h ah[2];
#pragma unroll
            for (int mi = 0; mi < 2; ++mi)
                ah[mi] = *(const v8h*)(A + abase[mi] + kc + ss * 32);
#pragma unroll
            for (int t = 0; t < TN; ++t) {
                const int fib = (ss * NTB + wc * TN + t) * 4 + q;
                const int off = (fib * 16 + r) * 8 + fib * 8;   // matches staging skew
                const v8h bh = *(const v8h*)&lbh[off];
#pragma unroll
                for (int mi = 0; mi < 2; ++mi)
                    acc[mi][t] = __builtin_amdgcn_mfma_f32_16x16x32_f16(ah[mi], bh, acc[mi][t], 0, 0, 0);
            }
        }
    }
    // C/D layout: col = lane&15, row = quad*4 + reg; store fp16
#pragma unroll
    for (int mi = 0; mi < 2; ++mi)
#pragma unroll
        for (int t = 0; t < TN; ++t)
#pragma unroll
            for (int i = 0; i < 4; ++i) {
                const int row = m0 + mi * 16 + q * 4 + i;
                if (row < M) H[(size_t)row * N + n0 + (wc * TN + t) * 16 + r] = (_Float16)acc[mi][t][i];
            }
    // fused attention-logit partials: each wave's columns lie in one head
    const int colbase = n0 + wc * TN * 16;
    const int hd = colbase >> 6;
#pragma unroll
    for (int mi = 0; mi < 2; ++mi)
#pragma unroll
        for (int i = 0; i < 4; ++i) {
            float sp = 0.f, dp = 0.f;
#pragma unroll
            for (int t = 0; t < TN; ++t) {
                const int col = colbase + t * 16 + r;
                sp += acc[mi][t][i] * aw_s[col];
                dp += acc[mi][t][i] * aw_d[col];
            }
#pragma unroll
            for (int m = 1; m < 16; m <<= 1) {
                sp += __shfl_xor(sp, m, 64);
                dp += __shfl_xor(dp, m, 64);
            }
            const int row = m0 + mi * 16 + q * 4 + i;
            if (r == 0 && row < M) {
                atomicAdd(&als[row * HS + hd], sp);
                atomicAdd(&ald[row * HS + hd], dp);
            }
        }
}

// ---------------- GAT aggregate, 2 waves per node, fp16 gather, 4-wide ----------------
// Epilogue writes a single fp16 activation plane (next GEMM's A operand).
__global__ __launch_bounds__(256) void k_agg4(const _Float16* __restrict__ hin,
                                              const float* __restrict__ als,
                                              const float* __restrict__ ald,
                                              const int* __restrict__ indptr,
                                              const int* __restrict__ esrc,
                                              const float* __restrict__ bias,
                                              const float* __restrict__ gamma,
                                              const float* __restrict__ beta,
                                              const float* __restrict__ mean,
                                              const float* __restrict__ var,
                                              _Float16* __restrict__ pho) {
    __shared__ float lacc[2][64][4];
    __shared__ float lsm[2][64];
    const int pair = threadIdx.x >> 7;          // node within block (0..1)
    const int wv   = (threadIdx.x >> 6) & 1;    // wave within pair
    const int lane = threadIdx.x & 63;
    const int n = blockIdx.x * 2 + pair;
    const int beg = indptr[n], end = indptr[n + 1];
    const int mid = beg + ((end - beg + 1) >> 1);
    const int e0 = wv ? mid : beg;
    const int e1 = wv ? end : mid;
    const int head = lane >> 4;
    const float aldn = ald[n * 4 + head];
    float4 acc = {0.f, 0.f, 0.f, 0.f};
    float sm = 0.f;
    const int c = lane * 4;
    int e = e0;
    for (; e + 3 < e1; e += 4) {       // 4 independent gather chains in flight
        const int s0 = esrc[e], s1 = esrc[e + 1], s2 = esrc[e + 2], s3 = esrc[e + 3];
        float v0 = als[s0 * 4 + head] + aldn;
        float v1 = als[s1 * 4 + head] + aldn;
        float v2 = als[s2 * 4 + head] + aldn;
        float v3 = als[s3 * 4 + head] + aldn;
        const v4h h0 = *(const v4h*)(hin + (size_t)s0 * 256 + c);
        const v4h h1 = *(const v4h*)(hin + (size_t)s1 * 256 + c);
        const v4h h2 = *(const v4h*)(hin + (size_t)s2 * 256 + c);
        const v4h h3 = *(const v4h*)(hin + (size_t)s3 * 256 + c);
        v0 = (v0 > 0.f) ? v0 : SLOPE * v0;
        v1 = (v1 > 0.f) ? v1 : SLOPE * v1;
        v2 = (v2 > 0.f) ? v2 : SLOPE * v2;
        v3 = (v3 > 0.f) ? v3 : SLOPE * v3;
        const float a0 = __expf(v0), a1 = __expf(v1), a2 = __expf(v2), a3 = __expf(v3);
        sm += (a0 + a1) + (a2 + a3);
        acc.x += a0 * (float)h0.x + a1 * (float)h1.x + a2 * (float)h2.x + a3 * (float)h3.x;
        acc.y += a0 * (float)h0.y + a1 * (float)h1.y + a2 * (float)h2.y + a3 * (float)h3.y;
        acc.z += a0 * (float)h0.z + a1 * (float)h1.z + a2 * (float)h2.z + a3 * (float)h3.z;
        acc.w += a0 * (float)h0.w + a1 * (float)h1.w + a2 * (float)h2.w + a3 * (float)h3.w;
    }
    for (; e < e1; ++e) {
        const int s0 = esrc[e];
        float v0 = als[s0 * 4 + head] + aldn;
        const v4h h0 = *(const v4h*)(hin + (size_t)s0 * 256 + c);
        v0 = (v0 > 0.f) ? v0 : SLOPE * v0;
        const float a0 = __expf(v0);
        sm += a0;
        acc.x += a0 * (float)h0.x; acc.y += a0 * (float)h0.y;
        acc.z += a0 * (float)h0.z; acc.w += a0 * (float)h0.w;
    }
    if (wv == 1) {
        lacc[pair][lane][0] = acc.x; lacc[pair][lane][1] = acc.y;
        lacc[pair][lane][2] = acc.z; lacc[pair][lane][3] = acc.w;
        lsm[pair][lane] = sm;
    }
    __syncthreads();
    if (wv == 0) {
        acc.x += lacc[pair][lane][0]; acc.y += lacc[pair][lane][1];
        acc.z += lacc[pair][lane][2]; acc.w += lacc[pair][lane][3];
        sm += lsm[pair][lane];
        const float invd = 1.f / (sm + 1e-16f);
        float y[4] = {acc.x * invd, acc.y * invd, acc.z * invd, acc.w * invd};
        v4h oh;
#pragma unroll
        for (int i = 0; i < 4; ++i) {
            float t = y[i] + bias[c + i];
            t = (t - mean[c + i]) * rsqrtf(var[c + i] + EPS_BN) * gamma[c + i] + beta[c + i];
            t = fmaxf(t, 0.f);
            oh[i] = (_Float16)t;
        }
        *(v4h*)(pho + (size_t)n * 256 + c) = oh;
    }
}

// ---------------- fused GAT aggregate (1 head) + bias + ReLU + pool-scatter ----------------
__global__ __launch_bounds__(256) void k_agg1(const _Float16* __restrict__ hin,
                                              const float* __restrict__ als,
                                              const float* __restrict__ ald,
                                              const int* __restrict__ indptr,
                                              const int* __restrict__ esrc,
                                              const float* __restrict__ bias,
                                              const int* __restrict__ batch,
                                              float* __restrict__ sums) {
    const int n = blockIdx.x * 4 + (threadIdx.x >> 6);
    const int lane = threadIdx.x & 63;
    const int beg = indptr[n], end = indptr[n + 1];
    const float aldn = ald[n];
    float acc = 0.f, sm = 0.f;
    int e = beg;
    for (; e + 3 < end; e += 4) {
        const int s0 = esrc[e], s1 = esrc[e + 1], s2 = esrc[e + 2], s3 = esrc[e + 3];
        float v0 = als[s0] + aldn;
        float v1 = als[s1] + aldn;
        float v2 = als[s2] + aldn;
        float v3 = als[s3] + aldn;
        const float h0 = (float)hin[(size_t)s0 * 64 + lane];
        const float h1 = (float)hin[(size_t)s1 * 64 + lane];
        const float h2 = (float)hin[(size_t)s2 * 64 + lane];
        const float h3 = (float)hin[(size_t)s3 * 64 + lane];
        v0 = (v0 > 0.f) ? v0 : SLOPE * v0;
        v1 = (v1 > 0.f) ? v1 : SLOPE * v1;
        v2 = (v2 > 0.f) ? v2 : SLOPE * v2;
        v3 = (v3 > 0.f) ? v3 : SLOPE * v3;
        const float a0 = __expf(v0), a1 = __expf(v1), a2 = __expf(v2), a3 = __expf(v3);
        sm += (a0 + a1) + (a2 + a3);
        acc += a0 * h0 + a1 * h1 + a2 * h2 + a3 * h3;
    }
    for (; e < end; ++e) {
        const int s0 = esrc[e];
        float v0 = als[s0] + aldn;
        const float h0 = (float)hin[(size_t)s0 * 64 + lane];
        v0 = (v0 > 0.f) ? v0 : SLOPE * v0;
        const float a0 = __expf(v0);
        sm += a0;
        acc += a0 * h0;
    }
    const float invd = 1.f / (sm + 1e-16f);
    const float val = fmaxf(acc * invd + bias[lane], 0.f);
    atomicAdd(&sums[batch[n] * 64 + lane], val);
}

__global__ void k_mlp(const float* __restrict__ sums, const int* __restrict__ gstart,
                      const float* __restrict__ w1, const float* __restrict__ b1,
                      const float* __restrict__ w2, const float* __restrict__ b2,
                      float* __restrict__ outp) {
    const int g = blockIdx.x;
    const int t = threadIdx.x;  // 32
    __shared__ float hid[32];
    const int cntn = gstart[g + 1] - gstart[g];
    const float inv = 1.f / (float)max(cntn, 1);
    float acc = b1[t];
    for (int c = 0; c < 64; ++c) acc += (sums[g * 64 + c] * inv) * w1[c * 32 + t];
    hid[t] = fmaxf(acc, 0.f);
    __syncthreads();
    if (t < N_CLASSES) {
        float o = b2[t];
        for (int k = 0; k < 32; ++k) o += hid[k] * w2[k * 5 + t];
        outp[g * 5 + t] = o;
    }
}

extern "C" void kernel_launch(void* const* d_in, const int* in_sizes, int n_in,
                              void* d_out, int out_size, void* d_ws, size_t ws_size,
                              hipStream_t stream) {
    const float* x        = (const float*)d_in[0];
    const int* edge_index = (const int*)d_in[1];
    const int* batch      = (const int*)d_in[2];
    const float* W1  = (const float*)d_in[3];
    const float* a1s = (const float*)d_in[4];
    const float* a1d = (const float*)d_in[5];
    const float* b1  = (const float*)d_in[6];
    const float* g1  = (const float*)d_in[7];
    const float* be1 = (const float*)d_in[8];
    const float* mu1 = (const float*)d_in[9];
    const float* va1 = (const float*)d_in[10];
    const float* W2  = (const float*)d_in[11];
    const float* a2s = (const float*)d_in[12];
    const float* a2d = (const float*)d_in[13];
    const float* b2  = (const float*)d_in[14];
    const float* g2  = (const float*)d_in[15];
    const float* be2 = (const float*)d_in[16];
    const float* mu2 = (const float*)d_in[17];
    const float* va2 = (const float*)d_in[18];
    const float* W3  = (const float*)d_in[19];
    const float* a3s = (const float*)d_in[20];
    const float* a3d = (const float*)d_in[21];
    const float* b3  = (const float*)d_in[22];
    const float* l1w = (const float*)d_in[23];
    const float* l1b = (const float*)d_in[24];
    const float* l2w = (const float*)d_in[25];
    const float* l2b = (const float*)d_in[26];
    float* out = (float*)d_out;

    char* w = (char*)d_ws;
    size_t off = 0;
    auto alloc = [&](size_t bytes) -> void* {
        void* p = w + off;
        off += (bytes + 255) & ~(size_t)255;
        return p;
    };
    _Float16* xh   = (_Float16*)alloc((size_t)N_NODES * 512 * 2);   // layer-1 A (fp16)
    _Float16* phf  = xh;                                            // activation plane (20000x256 fp16)
    _Float16* bufH  = (_Float16*)alloc((size_t)N_NODES * 256 * 2);  // GEMM1/2 out (fp16)
    _Float16* bufH3 = (_Float16*)alloc((size_t)N_NODES * 64 * 2);   // GEMM3 out (fp16)
    _Float16* bt1 = (_Float16*)alloc((size_t)512 * 256 * 2);
    _Float16* bt2 = (_Float16*)alloc((size_t)256 * 256 * 2);
    _Float16* bt3 = (_Float16*)alloc((size_t)256 * 64 * 2);
    float* albase = (float*)alloc((size_t)ALZ * 4);  // als1,ald1,als2,ald2,als3,ald3
    float* als1 = albase;
    float* ald1 = albase + 80000;
    float* als2 = albase + 160000;
    float* ald2 = albase + 240000;
    float* als3 = albase + 320000;
    float* ald3 = albase + 340000;
    int* cnt      = (int*)alloc((size_t)N_NODES * 4);
    int* wptr     = (int*)alloc((size_t)N_NODES * 4);
    int* indptr   = (int*)alloc((size_t)(N_NODES + 1) * 4);
    int* esrc     = (int*)alloc((size_t)E_TOT * 4);
    int* gstart   = (int*)alloc((size_t)(N_GRAPHS + 1) * 4);
    float* sums   = (float*)alloc((size_t)N_GRAPHS * 64 * 4);

    // fused prep (weight casts, x->fp16, gstart, all zero-inits)
    const int PREP_IDS = SPQ + W1E + W2E + W3E + N_NODES + N_NODES + N_GRAPHS * 64 + ALZ;
    k_prep<<<(PREP_IDS + 255) / 256, 256, 0, stream>>>(x, xh, W1, bt1, W2, bt2, W3, bt3,
                                                       batch, gstart, cnt, sums, albase);
    // CSR by dst (graph identical for all 3 layers)
    k_count<<<(E_TOT + 255) / 256, 256, 0, stream>>>(edge_index, cnt);
    k_scan<<<1, 1024, 0, stream>>>(cnt, indptr, wptr);
    k_scatter<<<(E_TOT + 255) / 256, 256, 0, stream>>>(edge_index, wptr, esrc);

    const int MB = (N_NODES + 63) / 64;  // 313 blocks of 64 rows

    // layer 1: A = fp16(x), B = fp16(W1), single f16-MFMA pass; logits fused
    k_gemm_mfma<4, 512><<<dim3(MB, 2), 256, 0, stream>>>(xh, bt1, bufH,
                                                         a1s, a1d, als1, ald1, 4,
                                                         N_NODES, 256);
    k_agg4<<<N_NODES / 2, 256, 0, stream>>>(bufH, als1, ald1, indptr, esrc, b1, g1, be1, mu1, va1, phf);
    // layer 2
    k_gemm_mfma<4, 256><<<dim3(MB, 2), 256, 0, stream>>>(phf, bt2, bufH,
                                                         a2s, a2d, als2, ald2, 4,
                                                         N_NODES, 256);
    k_agg4<<<N_NODES / 2, 256, 0, stream>>>(bufH, als2, ald2, indptr, esrc, b2, g2, be2, mu2, va2, phf);
    // layer 3
    k_gemm_mfma<2, 256><<<dim3(MB, 1), 256, 0, stream>>>(phf, bt3, bufH3,
                                                         a3s, a3d, als3, ald3, 1,
                                                         N_NODES, 64);
    k_agg1<<<N_NODES / 4, 256, 0, stream>>>(bufH3, als3, ald3, indptr, esrc, b3, batch, sums);
    // readout
    k_mlp<<<N_GRAPHS, 32, 0, stream>>>(sums, gstart, l1w, l1b, l2w, l2b, out);
}